// Round 7
// baseline (4472.043 us; speedup 1.0000x reference)
//
#include <hip/hip_runtime.h>
#include <hip/hip_bf16.h>

#define HID 128
#define IN_DIM 16
#define LDST 136   // LDS row stride in bf16 elems (272 B)
#define NBSH 6     // bucket = dst >> 6  (64 dsts/bucket)
#define BPAD 16    // bucket counter padding (ints) -> one 64B line per counter

typedef unsigned short u16;
typedef __attribute__((ext_vector_type(8))) short short8;
typedef __attribute__((ext_vector_type(4))) float f32x4;

__device__ __forceinline__ u16 f2b(float f) {  // RNE
    unsigned u = __float_as_uint(f);
    return (u16)((u + 0x7FFF + ((u >> 16) & 1)) >> 16);
}

// ---------------- graph prep ----------------

__global__ __launch_bounds__(256) void count_k(const int* __restrict__ dst, int* __restrict__ deg, int E) {
    int e = blockIdx.x * 256 + threadIdx.x;
    if (e < E) atomicAdd(&deg[dst[e]], 1);
}

// bucket sums: one wave per bucket of 64 dsts
__global__ __launch_bounds__(64) void bsum_k(const int* __restrict__ deg, int* __restrict__ bktcnt, int n) {
    int b = blockIdx.x;
    int i = (b << NBSH) + threadIdx.x;
    int v = (i < n) ? deg[i] : 0;
#pragma unroll
    for (int off = 1; off < 64; off <<= 1) v += __shfl_xor(v, off);
    if (threadIdx.x == 0) bktcnt[b] = v;
}

// scan 782 bucket sums -> bktbase (exclusive); seed padded bucket counters
__global__ __launch_bounds__(1024) void bscan_k(const int* __restrict__ bktcnt, int* __restrict__ bktbase,
                                                int* __restrict__ bcnt, int nb, int E) {
    __shared__ int sbuf[1024];
    int t = threadIdx.x;
    int v = (t < nb) ? bktcnt[t] : 0;
    sbuf[t] = v;
    __syncthreads();
    for (int off = 1; off < 1024; off <<= 1) {
        int a = (t >= off) ? sbuf[t - off] : 0;
        __syncthreads();
        sbuf[t] += a;
        __syncthreads();
    }
    if (t < nb) {
        int excl = sbuf[t] - v;
        bktbase[t] = excl;
        bcnt[t * BPAD] = excl;
    }
    if (t == 0) bktbase[nb] = E;
}

// scatter packed (src | (dst&63)<<26) into bucket-contiguous ebuf
__global__ __launch_bounds__(256) void bin_k(const int* __restrict__ src, const int* __restrict__ dst,
                                             int* __restrict__ bcnt, unsigned* __restrict__ ebuf, int E) {
    int e = blockIdx.x * 256 + threadIdx.x;
    if (e < E) {
        int d = dst[e];
        int q = atomicAdd(&bcnt[(d >> NBSH) * BPAD], 1);
        ebuf[q] = (unsigned)src[e] | ((unsigned)(d & 63) << 26);
    }
}

// ---------------- weight prep: fp32 [K,128] -> bf16 [128][K] (n-major) ----------------

struct WJobs {
    const float* src[16];
    int dstoff[16];
    int ks[16];  // log2 K
};

__global__ __launch_bounds__(256) void wprep_k(WJobs j, u16* __restrict__ Wt) {
    int m = blockIdx.x;
    const float* s = j.src[m];
    u16* d = Wt + j.dstoff[m];
    int ks = j.ks[m];
    int K = 1 << ks;
    int tot = K * HID;
    for (int idx = threadIdx.x; idx < tot; idx += 256) {
        int nn = idx >> ks;
        int kk = idx & (K - 1);
        d[idx] = f2b(s[kk * HID + nn]);
    }
}

// ---------------- message aggregation: block per bucket, LDS fp32 accumulators ----------------
// acc layout de-interleaved: acc[d*128 + l] = col 2l, acc[d*128 + 64 + l] = col 2l+1
// -> ds_add_f32 addresses are stride-1 over lanes: 2-way bank alias (free)

__global__ __launch_bounds__(256) void msg2_k(const u16* __restrict__ hb, const unsigned* __restrict__ ebuf,
                                              const int* __restrict__ bktbase, u16* __restrict__ msgb, int n) {
    __shared__ float acc[64 * HID];  // 32 KB
    int tid = threadIdx.x, lane = tid & 63, wave = tid >> 6;
    int b = blockIdx.x;
    for (int i = tid; i < 64 * HID; i += 256) acc[i] = 0.f;
    __syncthreads();

    int e0 = bktbase[b], e1 = bktbase[b + 1];
    int e = e0 + wave * 4;
    for (; e + 3 < e1; e += 16) {
        unsigned p0 = ebuf[e], p1 = ebuf[e + 1], p2 = ebuf[e + 2], p3 = ebuf[e + 3];
        unsigned v0 = *(const unsigned*)(hb + (size_t)(p0 & 0x3ffffffu) * HID + lane * 2);
        unsigned v1 = *(const unsigned*)(hb + (size_t)(p1 & 0x3ffffffu) * HID + lane * 2);
        unsigned v2 = *(const unsigned*)(hb + (size_t)(p2 & 0x3ffffffu) * HID + lane * 2);
        unsigned v3 = *(const unsigned*)(hb + (size_t)(p3 & 0x3ffffffu) * HID + lane * 2);
        int d0 = p0 >> 26, d1 = p1 >> 26, d2 = p2 >> 26, d3 = p3 >> 26;
        atomicAdd(&acc[d0 * HID + lane], __uint_as_float(v0 << 16));
        atomicAdd(&acc[d0 * HID + 64 + lane], __uint_as_float(v0 & 0xffff0000u));
        atomicAdd(&acc[d1 * HID + lane], __uint_as_float(v1 << 16));
        atomicAdd(&acc[d1 * HID + 64 + lane], __uint_as_float(v1 & 0xffff0000u));
        atomicAdd(&acc[d2 * HID + lane], __uint_as_float(v2 << 16));
        atomicAdd(&acc[d2 * HID + 64 + lane], __uint_as_float(v2 & 0xffff0000u));
        atomicAdd(&acc[d3 * HID + lane], __uint_as_float(v3 << 16));
        atomicAdd(&acc[d3 * HID + 64 + lane], __uint_as_float(v3 & 0xffff0000u));
    }
    int eend = e + 4; if (eend > e1) eend = e1;
    for (; e < eend; e++) {
        unsigned p = ebuf[e];
        unsigned v = *(const unsigned*)(hb + (size_t)(p & 0x3ffffffu) * HID + lane * 2);
        int d = p >> 26;
        atomicAdd(&acc[d * HID + lane], __uint_as_float(v << 16));
        atomicAdd(&acc[d * HID + 64 + lane], __uint_as_float(v & 0xffff0000u));
    }
    __syncthreads();

    int d0g = b << NBSH;
    for (int r = wave; r < 64; r += 4) {
        int row = d0g + r;
        if (row >= n) break;
        float ev = acc[r * HID + lane];
        float ov = acc[r * HID + 64 + lane];
        unsigned out = (unsigned)f2b(ev) | ((unsigned)f2b(ov) << 16);
        *(unsigned*)(msgb + (size_t)row * HID + lane * 2) = out;
    }
}

// ---------------- MFMA building blocks: 64x128 C-tile, 4 waves (2x2), 16x16x32 bf16 ----------------

__device__ __forceinline__ void stageA128(const u16* __restrict__ A, int row0, int tid, u16* sA) {
#pragma unroll
    for (int q = 0; q < 4; q++) {
        int c = tid + q * 256;
        int row = c >> 4, j8 = c & 15;
        uint4 v = *(const uint4*)(A + (size_t)(row0 + row) * HID + j8 * 8);
        *(uint4*)(sA + row * LDST + j8 * 8) = v;
    }
}

__device__ __forceinline__ void stageW128(const u16* __restrict__ Wt, int tid, u16* sB) {
#pragma unroll
    for (int q = 0; q < 8; q++) {
        int c = tid + q * 256;
        int row = c >> 4, j8 = c & 15;
        uint4 v = *(const uint4*)(Wt + row * HID + j8 * 8);
        *(uint4*)(sB + row * LDST + j8 * 8) = v;
    }
}

__device__ __forceinline__ void stageFeat(const float* __restrict__ feat, int row0, int n, int tid, u16* sA) {
    int row = tid >> 2, coff = tid & 3;
    ushort4 o = make_ushort4(0, 0, 0, 0);
    if (row0 + row < n) {
        float4 v = *(const float4*)(feat + (size_t)(row0 + row) * IN_DIM + coff * 4);
        o = make_ushort4(f2b(v.x), f2b(v.y), f2b(v.z), f2b(v.w));
    }
    *(ushort4*)(sA + row * LDST + coff * 4) = o;
    *(ushort4*)(sA + row * LDST + 16 + coff * 4) = make_ushort4(0, 0, 0, 0);  // zero-pad K 16->32
}

__device__ __forceinline__ void stageW16(const u16* __restrict__ Wt, int tid, u16* sB) {
    int row = tid >> 1, h8 = tid & 1;
    uint4 v = *(const uint4*)(Wt + row * IN_DIM + h8 * 8);
    *(uint4*)(sB + row * LDST + h8 * 8) = v;
    *(uint4*)(sB + row * LDST + 16 + h8 * 8) = make_uint4(0, 0, 0, 0);
}

template <int KSTEPS>
__device__ __forceinline__ void mac(const u16* sA, const u16* sB, int wrow, int wcol,
                                    int ln15, int quad, f32x4 acc[2][4]) {
#pragma unroll
    for (int kk = 0; kk < KSTEPS; kk++) {
        short8 a[2], b[4];
#pragma unroll
        for (int mi = 0; mi < 2; mi++)
            a[mi] = *(const short8*)(sA + (wrow + mi * 16 + ln15) * LDST + kk * 32 + quad * 8);
#pragma unroll
        for (int ni = 0; ni < 4; ni++)
            b[ni] = *(const short8*)(sB + (wcol + ni * 16 + ln15) * LDST + kk * 32 + quad * 8);
#pragma unroll
        for (int mi = 0; mi < 2; mi++)
#pragma unroll
            for (int ni = 0; ni < 4; ni++)
                acc[mi][ni] = __builtin_amdgcn_mfma_f32_16x16x32_bf16(a[mi], b[ni], acc[mi][ni], 0, 0, 0);
    }
}

__device__ __forceinline__ void set_bias(f32x4 acc[2][4], const float* __restrict__ bias, int wcol, int ln15) {
#pragma unroll
    for (int ni = 0; ni < 4; ni++) {
        float bv = bias[wcol + ni * 16 + ln15];
#pragma unroll
        for (int mi = 0; mi < 2; mi++) acc[mi][ni] = (f32x4){bv, bv, bv, bv};
    }
}

// relu(acc) -> sA in [row][col] layout (== next layer's A-operand layout)
__device__ __forceinline__ void acc_to_sA(const f32x4 acc[2][4], u16* sA, int wrow, int wcol,
                                          int ln15, int quad) {
#pragma unroll
    for (int mi = 0; mi < 2; mi++)
#pragma unroll
        for (int r = 0; r < 4; r++) {
            int row = wrow + mi * 16 + quad * 4 + r;
#pragma unroll
            for (int ni = 0; ni < 4; ni++)
                sA[row * LDST + wcol + ni * 16 + ln15] = f2b(fmaxf(acc[mi][ni][r], 0.f));
        }
}

// ---------------- fused init MLP: feat -> relu -> relu -> h (+hb) + colsum ----------------

__global__ __launch_bounds__(256, 3) void init_fused_k(const float* __restrict__ feat,
                                                       const u16* __restrict__ W0t, const u16* __restrict__ W1t,
                                                       const u16* __restrict__ W2t,
                                                       const float* __restrict__ b0, const float* __restrict__ b1,
                                                       const float* __restrict__ b2,
                                                       float* __restrict__ h, u16* __restrict__ hb,
                                                       float* __restrict__ gsum0, int n) {
    __shared__ u16 sA[64 * LDST];
    __shared__ u16 sB[128 * LDST];
    int tid = threadIdx.x;
    int lane = tid & 63, wave = tid >> 6;
    int ln15 = lane & 15, quad = lane >> 4;
    int wrow = (wave >> 1) * 32, wcol = (wave & 1) * 64;
    int row0 = blockIdx.x * 64;
    f32x4 acc[2][4];

    stageFeat(feat, row0, n, tid, sA);
    stageW16(W0t, tid, sB);
    set_bias(acc, b0, wcol, ln15);
    __syncthreads();
    mac<1>(sA, sB, wrow, wcol, ln15, quad, acc);
    __syncthreads();
    acc_to_sA(acc, sA, wrow, wcol, ln15, quad);
    stageW128(W1t, tid, sB);
    set_bias(acc, b1, wcol, ln15);
    __syncthreads();
    mac<4>(sA, sB, wrow, wcol, ln15, quad, acc);
    __syncthreads();
    acc_to_sA(acc, sA, wrow, wcol, ln15, quad);
    stageW128(W2t, tid, sB);
    set_bias(acc, b2, wcol, ln15);
    __syncthreads();
    mac<4>(sA, sB, wrow, wcol, ln15, quad, acc);

    float csum[4] = {0.f, 0.f, 0.f, 0.f};
#pragma unroll
    for (int mi = 0; mi < 2; mi++)
#pragma unroll
        for (int r = 0; r < 4; r++) {
            int row = row0 + wrow + mi * 16 + quad * 4 + r;
            if (row < n) {
#pragma unroll
                for (int ni = 0; ni < 4; ni++) {
                    float v = acc[mi][ni][r];
                    int col = wcol + ni * 16 + ln15;
                    h[(size_t)row * HID + col] = v;
                    hb[(size_t)row * HID + col] = f2b(v);
                    csum[ni] += v;
                }
            }
        }
    __syncthreads();
    float* s_cs = (float*)sA;
    if (tid < HID) s_cs[tid] = 0.f;
    __syncthreads();
#pragma unroll
    for (int ni = 0; ni < 4; ni++) {
        float p = csum[ni];
        p += __shfl_xor(p, 16);
        p += __shfl_xor(p, 32);
        if (quad == 0) atomicAdd(&s_cs[wcol + ni * 16 + ln15], p);
    }
    __syncthreads();
    if (tid < HID) atomicAdd(&gsum0[tid], s_cs[tid]);
}

// ---------------- fused node update ----------------

template <bool COLSUM>
__global__ __launch_bounds__(256, 3) void node_fused_k(const u16* __restrict__ msgb, const u16* __restrict__ hbin,
                                                       const u16* __restrict__ W0a, const u16* __restrict__ W0b,
                                                       const u16* __restrict__ W1t, const u16* __restrict__ W2t,
                                                       const float* __restrict__ b0, const float* __restrict__ Wg,
                                                       const float* __restrict__ gsumIn,
                                                       const float* __restrict__ b1, const float* __restrict__ b2,
                                                       const int* __restrict__ deg,
                                                       float* __restrict__ h, u16* __restrict__ hb,
                                                       float* __restrict__ gsumOut, int n) {
    __shared__ u16 sA[64 * LDST];
    __shared__ u16 sB[128 * LDST];
    __shared__ float s_gr[HID];
    __shared__ float s_grW[HID];
    __shared__ float s_red[2];
    int tid = threadIdx.x;
    int lane = tid & 63, wave = tid >> 6;
    int ln15 = lane & 15, quad = lane >> 4;
    int wrow = (wave >> 1) * 32, wcol = (wave & 1) * 64;
    int row0 = blockIdx.x * 64;
    f32x4 acc[2][4];

    stageA128(msgb, row0, tid, sA);
    stageW128(W0a, tid, sB);
    if (tid < HID) {
        float g = gsumIn[tid];
        float s = g * g;
#pragma unroll
        for (int off = 1; off < 64; off <<= 1) s += __shfl_xor(s, off);
        if ((tid & 63) == 0) s_red[tid >> 6] = s;
    }
    __syncthreads();
    if (tid < HID) {
        float inv = 1.f / (sqrtf(s_red[0] + s_red[1]) + 1e-8f);
        s_gr[tid] = gsumIn[tid] * inv;
    }
    __syncthreads();
    if (tid < HID) {
        float a = b0[tid];
#pragma unroll 4
        for (int k = 0; k < HID; k++) a += s_gr[k] * Wg[k * HID + tid];
        s_grW[tid] = a;
    }
    __syncthreads();
    set_bias(acc, s_grW, wcol, ln15);
    mac<4>(sA, sB, wrow, wcol, ln15, quad, acc);     // msg @ W0a
    __syncthreads();
    stageA128(hbin, row0, tid, sA);
    stageW128(W0b, tid, sB);
    __syncthreads();
    mac<4>(sA, sB, wrow, wcol, ln15, quad, acc);     // + h @ W0b
    __syncthreads();
    acc_to_sA(acc, sA, wrow, wcol, ln15, quad);
    stageW128(W1t, tid, sB);
    set_bias(acc, b1, wcol, ln15);
    __syncthreads();
    mac<4>(sA, sB, wrow, wcol, ln15, quad, acc);
    __syncthreads();
    acc_to_sA(acc, sA, wrow, wcol, ln15, quad);
    stageW128(W2t, tid, sB);
    set_bias(acc, b2, wcol, ln15);
    __syncthreads();
    mac<4>(sA, sB, wrow, wcol, ln15, quad, acc);

    __syncthreads();
    float* s_rs = (float*)sA;             // [64] row sum-of-squares
    float* s_cs = (float*)sA + 64;        // [128] col sums
    if (tid < 64) s_rs[tid] = 0.f;
    else if (tid < 192) s_cs[tid - 64] = 0.f;
    __syncthreads();
#pragma unroll
    for (int mi = 0; mi < 2; mi++)
#pragma unroll
        for (int r = 0; r < 4; r++) {
            float p = 0.f;
#pragma unroll
            for (int ni = 0; ni < 4; ni++) { float v = acc[mi][ni][r]; p += v * v; }
            p += __shfl_xor(p, 1); p += __shfl_xor(p, 2);
            p += __shfl_xor(p, 4); p += __shfl_xor(p, 8);
            if (ln15 == 0) atomicAdd(&s_rs[wrow + mi * 16 + quad * 4 + r], p);
        }
    __syncthreads();
    float csum[4] = {0.f, 0.f, 0.f, 0.f};
#pragma unroll
    for (int mi = 0; mi < 2; mi++)
#pragma unroll
        for (int r = 0; r < 4; r++) {
            int rl = wrow + mi * 16 + quad * 4 + r;
            int row = row0 + rl;
            if (row < n) {
                bool upd = deg[row] > 0;
                float inv = 1.f / (sqrtf(s_rs[rl]) + 1e-8f);
#pragma unroll
                for (int ni = 0; ni < 4; ni++) {
                    int col = wcol + ni * 16 + ln15;
                    float v;
                    if (upd) {
                        v = acc[mi][ni][r] * inv;
                        h[(size_t)row * HID + col] = v;
                        hb[(size_t)row * HID + col] = f2b(v);
                    } else {
                        v = COLSUM ? h[(size_t)row * HID + col] : 0.f;
                    }
                    if (COLSUM) csum[ni] += v;
                }
            }
        }
    if (COLSUM) {
#pragma unroll
        for (int ni = 0; ni < 4; ni++) {
            float p = csum[ni];
            p += __shfl_xor(p, 16);
            p += __shfl_xor(p, 32);
            if (quad == 0) atomicAdd(&s_cs[wcol + ni * 16 + ln15], p);
        }
        __syncthreads();
        if (tid < HID) atomicAdd(&gsumOut[tid], s_cs[tid]);
    }
}

// ---------------- launch ----------------

static inline char* align_up(char* p, size_t a) {
    return (char*)(((uintptr_t)p + a - 1) & ~(uintptr_t)(a - 1));
}

extern "C" void kernel_launch(void* const* d_in, const int* in_sizes, int n_in,
                              void* d_out, int out_size, void* d_ws, size_t ws_size,
                              hipStream_t stream) {
    const float* feat = (const float*)d_in[0];
    const int* src = (const int*)d_in[1];
    const int* dst = (const int*)d_in[2];
    const float* iW0 = (const float*)d_in[3];
    const float* ib0 = (const float*)d_in[4];
    const float* iW1 = (const float*)d_in[5];
    const float* ib1 = (const float*)d_in[6];
    const float* iW2 = (const float*)d_in[7];
    const float* ib2 = (const float*)d_in[8];
    const float* nW0 = (const float*)d_in[9];
    const float* nb0 = (const float*)d_in[10];
    const float* nW1 = (const float*)d_in[11];
    const float* nb1 = (const float*)d_in[12];
    const float* nW2 = (const float*)d_in[13];
    const float* nb2 = (const float*)d_in[14];

    int N = in_sizes[0] / IN_DIM;
    int E = in_sizes[1];
    int n_iter = in_sizes[10] / HID;
    int NB = (N + (1 << NBSH) - 1) >> NBSH;   // 782 for N=50000 (<=1024 assumed in bscan_k)
    float* h = (float*)d_out;

    char* w = (char*)d_ws;
    size_t big2 = (size_t)(N + 64) * HID * sizeof(u16);
    u16* hb   = (u16*)w; w += big2;
    u16* msgb = (u16*)w; w += big2;
    float* gsums = (float*)w; w += (size_t)(n_iter + 1) * HID * sizeof(float);
    u16* Wt = (u16*)w; w += (size_t)(2048 + 2 * 16384 + n_iter * 4 * 16384) * sizeof(u16);
    w = align_up(w, 16);
    int* deg = (int*)w; w += (size_t)N * 4;  w = align_up(w, 16);
    int* bktcnt = (int*)w; w += (size_t)NB * 4;  w = align_up(w, 16);
    int* bktbase = (int*)w; w += (size_t)(NB + 1) * 4;  w = align_up(w, 64);
    int* bcnt = (int*)w; w += (size_t)NB * BPAD * 4;  w = align_up(w, 16);
    unsigned* ebuf = (unsigned*)w; w += (size_t)E * 4;
    (void)ws_size; (void)n_in; (void)out_size;

    // Wt layout offsets (bf16 elems)
    const int OFF_IW0 = 0;
    const int OFF_IW1 = 2048;
    const int OFF_IW2 = 2048 + 16384;
    const int OFF_IT = 2048 + 2 * 16384;  // per iter: W0a, W0b, W1, W2 (4 x 16384)

    WJobs jobs;
    int nj = 0;
    jobs.src[nj] = iW0; jobs.dstoff[nj] = OFF_IW0; jobs.ks[nj] = 4; nj++;
    jobs.src[nj] = iW1; jobs.dstoff[nj] = OFF_IW1; jobs.ks[nj] = 7; nj++;
    jobs.src[nj] = iW2; jobs.dstoff[nj] = OFF_IW2; jobs.ks[nj] = 7; nj++;
    for (int i = 0; i < n_iter && nj + 4 <= 16; i++) {
        int base = OFF_IT + i * 4 * 16384;
        jobs.src[nj] = nW0 + (size_t)i * 3 * HID * HID;               jobs.dstoff[nj] = base;             jobs.ks[nj] = 7; nj++;
        jobs.src[nj] = nW0 + (size_t)i * 3 * HID * HID + HID * HID;   jobs.dstoff[nj] = base + 16384;     jobs.ks[nj] = 7; nj++;
        jobs.src[nj] = nW1 + (size_t)i * HID * HID;                   jobs.dstoff[nj] = base + 2 * 16384; jobs.ks[nj] = 7; nj++;
        jobs.src[nj] = nW2 + (size_t)i * HID * HID;                   jobs.dstoff[nj] = base + 3 * 16384; jobs.ks[nj] = 7; nj++;
    }

    hipMemsetAsync(deg, 0, (size_t)N * 4, stream);
    hipMemsetAsync(gsums, 0, (size_t)(n_iter + 1) * HID * sizeof(float), stream);

    wprep_k<<<nj, 256, 0, stream>>>(jobs, Wt);

    int eg = (E + 255) / 256;
    count_k<<<eg, 256, 0, stream>>>(dst, deg, E);
    bsum_k<<<NB, 64, 0, stream>>>(deg, bktcnt, N);
    bscan_k<<<1, 1024, 0, stream>>>(bktcnt, bktbase, bcnt, NB, E);
    bin_k<<<eg, 256, 0, stream>>>(src, dst, bcnt, ebuf, E);

    int gb = (N + 63) / 64;
    init_fused_k<<<gb, 256, 0, stream>>>(feat, Wt + OFF_IW0, Wt + OFF_IW1, Wt + OFF_IW2,
                                         ib0, ib1, ib2, h, hb, gsums, N);

    for (int i = 0; i < n_iter; i++) {
        const u16* Wit = Wt + OFF_IT + (size_t)i * 4 * 16384;
        const float* Wg = nW0 + (size_t)i * 3 * HID * HID + 2 * HID * HID;
        msg2_k<<<NB, 256, 0, stream>>>(hb, ebuf, bktbase, msgb, N);
        if (i + 1 < n_iter) {
            node_fused_k<true><<<gb, 256, 0, stream>>>(msgb, hb, Wit, Wit + 16384, Wit + 2 * 16384,
                                                       Wit + 3 * 16384, nb0 + (size_t)i * HID, Wg,
                                                       gsums + (size_t)i * HID, nb1 + (size_t)i * HID,
                                                       nb2 + (size_t)i * HID, deg, h, hb,
                                                       gsums + (size_t)(i + 1) * HID, N);
        } else {
            node_fused_k<false><<<gb, 256, 0, stream>>>(msgb, hb, Wit, Wit + 16384, Wit + 2 * 16384,
                                                        Wit + 3 * 16384, nb0 + (size_t)i * HID, Wg,
                                                        gsums + (size_t)i * HID, nb1 + (size_t)i * HID,
                                                        nb2 + (size_t)i * HID, deg, h, hb,
                                                        nullptr, N);
        }
    }
}

// Round 8
// 727.433 us; speedup vs baseline: 6.1477x; 6.1477x over previous
//
#include <hip/hip_runtime.h>
#include <hip/hip_bf16.h>

#define HID 128
#define IN_DIM 16
#define LDST 136   // LDS row stride in bf16 elems (272 B)
#define NBSH 6     // bucket = dst >> 6  (64 dsts/bucket)
#define BPAD 16    // bucket counter padding (ints) -> one 64B line per counter
#define SRCM 0x3ffffffu

typedef unsigned short u16;
typedef __attribute__((ext_vector_type(8))) short short8;
typedef __attribute__((ext_vector_type(4))) float f32x4;

__device__ __forceinline__ u16 f2b(float f) {  // RNE
    unsigned u = __float_as_uint(f);
    return (u16)((u + 0x7FFF + ((u >> 16) & 1)) >> 16);
}

// ---------------- graph prep ----------------

__global__ __launch_bounds__(256) void count_k(const int* __restrict__ dst, int* __restrict__ deg, int E) {
    int e = blockIdx.x * 256 + threadIdx.x;
    if (e < E) atomicAdd(&deg[dst[e]], 1);
}

// bucket sums: one wave per bucket of 64 dsts
__global__ __launch_bounds__(64) void bsum_k(const int* __restrict__ deg, int* __restrict__ bktcnt, int n) {
    int b = blockIdx.x;
    int i = (b << NBSH) + threadIdx.x;
    int v = (i < n) ? deg[i] : 0;
#pragma unroll
    for (int off = 1; off < 64; off <<= 1) v += __shfl_xor(v, off);
    if (threadIdx.x == 0) bktcnt[b] = v;
}

// scan bucket sums (nb <= 1024) -> bktbase (exclusive); seed padded bucket counters
__global__ __launch_bounds__(1024) void bscan_k(const int* __restrict__ bktcnt, int* __restrict__ bktbase,
                                                int* __restrict__ bcnt, int nb, int E) {
    __shared__ int sbuf[1024];
    int t = threadIdx.x;
    int v = (t < nb) ? bktcnt[t] : 0;
    sbuf[t] = v;
    __syncthreads();
    for (int off = 1; off < 1024; off <<= 1) {
        int a = (t >= off) ? sbuf[t - off] : 0;
        __syncthreads();
        sbuf[t] += a;
        __syncthreads();
    }
    if (t < nb) {
        int excl = sbuf[t] - v;
        bktbase[t] = excl;
        bcnt[t * BPAD] = excl;
    }
    if (t == 0) bktbase[nb] = E;
}

// per-dst row_ptr from bucket bases: wave per bucket, shuffle prefix over 64 degs; seed cnt
__global__ __launch_bounds__(256) void rptr_k(const int* __restrict__ deg, const int* __restrict__ bktbase,
                                              int* __restrict__ row_ptr, int* __restrict__ cnt,
                                              int n, int nb, int E) {
    int wave = threadIdx.x >> 6, lane = threadIdx.x & 63;
    int b = blockIdx.x * 4 + wave;
    if (b >= nb) return;
    int i = (b << NBSH) + lane;
    int d = (i < n) ? deg[i] : 0;
    int s = d;
#pragma unroll
    for (int off = 1; off < 64; off <<= 1) {
        int t = __shfl_up(s, off);
        if (lane >= off) s += t;
    }
    int rp = bktbase[b] + s - d;  // exclusive
    if (i < n) { row_ptr[i] = rp; cnt[i] = rp; }
    if (i == n - 1) row_ptr[n] = E;
}

// scatter packed (src | (dst&63)<<26) into bucket-contiguous ebuf
__global__ __launch_bounds__(256) void bin_k(const int* __restrict__ src, const int* __restrict__ dst,
                                             int* __restrict__ bcnt, unsigned* __restrict__ ebuf, int E) {
    int e = blockIdx.x * 256 + threadIdx.x;
    if (e < E) {
        int d = dst[e];
        int q = atomicAdd(&bcnt[(d >> NBSH) * BPAD], 1);
        ebuf[q] = (unsigned)src[e] | ((unsigned)(d & 63) << 26);
    }
}

// block per bucket: final scatter within small window (block-local writes, L2-merged)
__global__ __launch_bounds__(256) void fill2_k(const unsigned* __restrict__ ebuf, const int* __restrict__ bktbase,
                                               int* __restrict__ cnt, int* __restrict__ srcs, int n) {
    int b = blockIdx.x;
    int e0 = bktbase[b], e1 = bktbase[b + 1];
    int d0 = b << NBSH;
    for (int i = e0 + threadIdx.x; i < e1; i += 256) {
        unsigned p = ebuf[i];
        int d = d0 | (int)(p >> 26);
        int pos = atomicAdd(&cnt[d], 1);
        srcs[pos] = (int)(p & SRCM);
    }
}

// ---------------- weight prep: fp32 [K,128] -> bf16 [128][K] (n-major) ----------------

struct WJobs {
    const float* src[16];
    int dstoff[16];
    int ks[16];  // log2 K
};

__global__ __launch_bounds__(256) void wprep_k(WJobs j, u16* __restrict__ Wt) {
    int m = blockIdx.x;
    const float* s = j.src[m];
    u16* d = Wt + j.dstoff[m];
    int ks = j.ks[m];
    int K = 1 << ks;
    int tot = K * HID;
    for (int idx = threadIdx.x; idx < tot; idx += 256) {
        int nn = idx >> ks;
        int kk = idx & (K - 1);
        d[idx] = f2b(s[kk * HID + nn]);
    }
}

// ---------------- message aggregation: gather bf16 h rows, wave per dst (CSR) ----------------

__global__ __launch_bounds__(256) void msg_k(const u16* __restrict__ hb, const int* __restrict__ row_ptr,
                                             const int* __restrict__ srcs, u16* __restrict__ msgb, int n) {
    int wave = threadIdx.x >> 6, lane = threadIdx.x & 63;
    int d = blockIdx.x * 4 + wave;
    if (d >= n) return;
    int e = row_ptr[d], e1 = row_ptr[d + 1];
    float a0 = 0.f, a1 = 0.f;
    for (; e + 3 < e1; e += 4) {
        int s0 = srcs[e], s1 = srcs[e + 1], s2 = srcs[e + 2], s3 = srcs[e + 3];
        unsigned v0 = *(const unsigned*)(hb + (size_t)s0 * HID + lane * 2);
        unsigned v1 = *(const unsigned*)(hb + (size_t)s1 * HID + lane * 2);
        unsigned v2 = *(const unsigned*)(hb + (size_t)s2 * HID + lane * 2);
        unsigned v3 = *(const unsigned*)(hb + (size_t)s3 * HID + lane * 2);
        a0 += __uint_as_float(v0 << 16) + __uint_as_float(v1 << 16) +
              __uint_as_float(v2 << 16) + __uint_as_float(v3 << 16);
        a1 += __uint_as_float(v0 & 0xffff0000u) + __uint_as_float(v1 & 0xffff0000u) +
              __uint_as_float(v2 & 0xffff0000u) + __uint_as_float(v3 & 0xffff0000u);
    }
    for (; e < e1; e++) {
        unsigned v = *(const unsigned*)(hb + (size_t)srcs[e] * HID + lane * 2);
        a0 += __uint_as_float(v << 16);
        a1 += __uint_as_float(v & 0xffff0000u);
    }
    unsigned out = (unsigned)f2b(a0) | ((unsigned)f2b(a1) << 16);
    *(unsigned*)(msgb + (size_t)d * HID + lane * 2) = out;
}

// ---------------- MFMA building blocks: 64x128 C-tile, 4 waves (2x2), 16x16x32 bf16 ----------------

__device__ __forceinline__ void stageA128(const u16* __restrict__ A, int row0, int tid, u16* sA) {
#pragma unroll
    for (int q = 0; q < 4; q++) {
        int c = tid + q * 256;
        int row = c >> 4, j8 = c & 15;
        uint4 v = *(const uint4*)(A + (size_t)(row0 + row) * HID + j8 * 8);
        *(uint4*)(sA + row * LDST + j8 * 8) = v;
    }
}

__device__ __forceinline__ void stageW128(const u16* __restrict__ Wt, int tid, u16* sB) {
#pragma unroll
    for (int q = 0; q < 8; q++) {
        int c = tid + q * 256;
        int row = c >> 4, j8 = c & 15;
        uint4 v = *(const uint4*)(Wt + row * HID + j8 * 8);
        *(uint4*)(sB + row * LDST + j8 * 8) = v;
    }
}

__device__ __forceinline__ void stageFeat(const float* __restrict__ feat, int row0, int n, int tid, u16* sA) {
    int row = tid >> 2, coff = tid & 3;
    ushort4 o = make_ushort4(0, 0, 0, 0);
    if (row0 + row < n) {
        float4 v = *(const float4*)(feat + (size_t)(row0 + row) * IN_DIM + coff * 4);
        o = make_ushort4(f2b(v.x), f2b(v.y), f2b(v.z), f2b(v.w));
    }
    *(ushort4*)(sA + row * LDST + coff * 4) = o;
    *(ushort4*)(sA + row * LDST + 16 + coff * 4) = make_ushort4(0, 0, 0, 0);  // zero-pad K 16->32
}

__device__ __forceinline__ void stageW16(const u16* __restrict__ Wt, int tid, u16* sB) {
    int row = tid >> 1, h8 = tid & 1;
    uint4 v = *(const uint4*)(Wt + row * IN_DIM + h8 * 8);
    *(uint4*)(sB + row * LDST + h8 * 8) = v;
    *(uint4*)(sB + row * LDST + 16 + h8 * 8) = make_uint4(0, 0, 0, 0);
}

template <int KSTEPS>
__device__ __forceinline__ void mac(const u16* sA, const u16* sB, int wrow, int wcol,
                                    int ln15, int quad, f32x4 acc[2][4]) {
#pragma unroll
    for (int kk = 0; kk < KSTEPS; kk++) {
        short8 a[2], b[4];
#pragma unroll
        for (int mi = 0; mi < 2; mi++)
            a[mi] = *(const short8*)(sA + (wrow + mi * 16 + ln15) * LDST + kk * 32 + quad * 8);
#pragma unroll
        for (int ni = 0; ni < 4; ni++)
            b[ni] = *(const short8*)(sB + (wcol + ni * 16 + ln15) * LDST + kk * 32 + quad * 8);
#pragma unroll
        for (int mi = 0; mi < 2; mi++)
#pragma unroll
            for (int ni = 0; ni < 4; ni++)
                acc[mi][ni] = __builtin_amdgcn_mfma_f32_16x16x32_bf16(a[mi], b[ni], acc[mi][ni], 0, 0, 0);
    }
}

__device__ __forceinline__ void set_bias(f32x4 acc[2][4], const float* __restrict__ bias, int wcol, int ln15) {
#pragma unroll
    for (int ni = 0; ni < 4; ni++) {
        float bv = bias[wcol + ni * 16 + ln15];
#pragma unroll
        for (int mi = 0; mi < 2; mi++) acc[mi][ni] = (f32x4){bv, bv, bv, bv};
    }
}

// relu(acc) -> sA in [row][col] layout (== next layer's A-operand layout)
__device__ __forceinline__ void acc_to_sA(const f32x4 acc[2][4], u16* sA, int wrow, int wcol,
                                          int ln15, int quad) {
#pragma unroll
    for (int mi = 0; mi < 2; mi++)
#pragma unroll
        for (int r = 0; r < 4; r++) {
            int row = wrow + mi * 16 + quad * 4 + r;
#pragma unroll
            for (int ni = 0; ni < 4; ni++)
                sA[row * LDST + wcol + ni * 16 + ln15] = f2b(fmaxf(acc[mi][ni][r], 0.f));
        }
}

// ---------------- fused init MLP: feat -> relu -> relu -> h (+hb) + colsum ----------------

__global__ __launch_bounds__(256, 3) void init_fused_k(const float* __restrict__ feat,
                                                       const u16* __restrict__ W0t, const u16* __restrict__ W1t,
                                                       const u16* __restrict__ W2t,
                                                       const float* __restrict__ b0, const float* __restrict__ b1,
                                                       const float* __restrict__ b2,
                                                       float* __restrict__ h, u16* __restrict__ hb,
                                                       float* __restrict__ gsum0, int n) {
    __shared__ u16 sA[64 * LDST];
    __shared__ u16 sB[128 * LDST];
    int tid = threadIdx.x;
    int lane = tid & 63, wave = tid >> 6;
    int ln15 = lane & 15, quad = lane >> 4;
    int wrow = (wave >> 1) * 32, wcol = (wave & 1) * 64;
    int row0 = blockIdx.x * 64;
    f32x4 acc[2][4];

    stageFeat(feat, row0, n, tid, sA);
    stageW16(W0t, tid, sB);
    set_bias(acc, b0, wcol, ln15);
    __syncthreads();
    mac<1>(sA, sB, wrow, wcol, ln15, quad, acc);
    __syncthreads();
    acc_to_sA(acc, sA, wrow, wcol, ln15, quad);
    stageW128(W1t, tid, sB);
    set_bias(acc, b1, wcol, ln15);
    __syncthreads();
    mac<4>(sA, sB, wrow, wcol, ln15, quad, acc);
    __syncthreads();
    acc_to_sA(acc, sA, wrow, wcol, ln15, quad);
    stageW128(W2t, tid, sB);
    set_bias(acc, b2, wcol, ln15);
    __syncthreads();
    mac<4>(sA, sB, wrow, wcol, ln15, quad, acc);

    float csum[4] = {0.f, 0.f, 0.f, 0.f};
#pragma unroll
    for (int mi = 0; mi < 2; mi++)
#pragma unroll
        for (int r = 0; r < 4; r++) {
            int row = row0 + wrow + mi * 16 + quad * 4 + r;
            if (row < n) {
#pragma unroll
                for (int ni = 0; ni < 4; ni++) {
                    float v = acc[mi][ni][r];
                    int col = wcol + ni * 16 + ln15;
                    h[(size_t)row * HID + col] = v;
                    hb[(size_t)row * HID + col] = f2b(v);
                    csum[ni] += v;
                }
            }
        }
    __syncthreads();
    float* s_cs = (float*)sA;
    if (tid < HID) s_cs[tid] = 0.f;
    __syncthreads();
#pragma unroll
    for (int ni = 0; ni < 4; ni++) {
        float p = csum[ni];
        p += __shfl_xor(p, 16);
        p += __shfl_xor(p, 32);
        if (quad == 0) atomicAdd(&s_cs[wcol + ni * 16 + ln15], p);
    }
    __syncthreads();
    if (tid < HID) atomicAdd(&gsum0[tid], s_cs[tid]);
}

// ---------------- fused node update ----------------

template <bool COLSUM>
__global__ __launch_bounds__(256, 3) void node_fused_k(const u16* __restrict__ msgb, const u16* __restrict__ hbin,
                                                       const u16* __restrict__ W0a, const u16* __restrict__ W0b,
                                                       const u16* __restrict__ W1t, const u16* __restrict__ W2t,
                                                       const float* __restrict__ b0, const float* __restrict__ Wg,
                                                       const float* __restrict__ gsumIn,
                                                       const float* __restrict__ b1, const float* __restrict__ b2,
                                                       const int* __restrict__ deg,
                                                       float* __restrict__ h, u16* __restrict__ hb,
                                                       float* __restrict__ gsumOut, int n) {
    __shared__ u16 sA[64 * LDST];
    __shared__ u16 sB[128 * LDST];
    __shared__ float s_gr[HID];
    __shared__ float s_grW[HID];
    __shared__ float s_red[2];
    int tid = threadIdx.x;
    int lane = tid & 63, wave = tid >> 6;
    int ln15 = lane & 15, quad = lane >> 4;
    int wrow = (wave >> 1) * 32, wcol = (wave & 1) * 64;
    int row0 = blockIdx.x * 64;
    f32x4 acc[2][4];

    stageA128(msgb, row0, tid, sA);
    stageW128(W0a, tid, sB);
    if (tid < HID) {
        float g = gsumIn[tid];
        float s = g * g;
#pragma unroll
        for (int off = 1; off < 64; off <<= 1) s += __shfl_xor(s, off);
        if ((tid & 63) == 0) s_red[tid >> 6] = s;
    }
    __syncthreads();
    if (tid < HID) {
        float inv = 1.f / (sqrtf(s_red[0] + s_red[1]) + 1e-8f);
        s_gr[tid] = gsumIn[tid] * inv;
    }
    __syncthreads();
    if (tid < HID) {
        float a = b0[tid];
#pragma unroll 4
        for (int k = 0; k < HID; k++) a += s_gr[k] * Wg[k * HID + tid];
        s_grW[tid] = a;
    }
    __syncthreads();
    set_bias(acc, s_grW, wcol, ln15);
    mac<4>(sA, sB, wrow, wcol, ln15, quad, acc);     // msg @ W0a
    __syncthreads();
    stageA128(hbin, row0, tid, sA);
    stageW128(W0b, tid, sB);
    __syncthreads();
    mac<4>(sA, sB, wrow, wcol, ln15, quad, acc);     // + h @ W0b
    __syncthreads();
    acc_to_sA(acc, sA, wrow, wcol, ln15, quad);
    stageW128(W1t, tid, sB);
    set_bias(acc, b1, wcol, ln15);
    __syncthreads();
    mac<4>(sA, sB, wrow, wcol, ln15, quad, acc);
    __syncthreads();
    acc_to_sA(acc, sA, wrow, wcol, ln15, quad);
    stageW128(W2t, tid, sB);
    set_bias(acc, b2, wcol, ln15);
    __syncthreads();
    mac<4>(sA, sB, wrow, wcol, ln15, quad, acc);

    __syncthreads();
    float* s_rs = (float*)sA;             // [64] row sum-of-squares
    float* s_cs = (float*)sA + 64;        // [128] col sums
    if (tid < 64) s_rs[tid] = 0.f;
    else if (tid < 192) s_cs[tid - 64] = 0.f;
    __syncthreads();
#pragma unroll
    for (int mi = 0; mi < 2; mi++)
#pragma unroll
        for (int r = 0; r < 4; r++) {
            float p = 0.f;
#pragma unroll
            for (int ni = 0; ni < 4; ni++) { float v = acc[mi][ni][r]; p += v * v; }
            p += __shfl_xor(p, 1); p += __shfl_xor(p, 2);
            p += __shfl_xor(p, 4); p += __shfl_xor(p, 8);
            if (ln15 == 0) atomicAdd(&s_rs[wrow + mi * 16 + quad * 4 + r], p);
        }
    __syncthreads();
    float csum[4] = {0.f, 0.f, 0.f, 0.f};
#pragma unroll
    for (int mi = 0; mi < 2; mi++)
#pragma unroll
        for (int r = 0; r < 4; r++) {
            int rl = wrow + mi * 16 + quad * 4 + r;
            int row = row0 + rl;
            if (row < n) {
                bool upd = deg[row] > 0;
                float inv = 1.f / (sqrtf(s_rs[rl]) + 1e-8f);
#pragma unroll
                for (int ni = 0; ni < 4; ni++) {
                    int col = wcol + ni * 16 + ln15;
                    float v;
                    if (upd) {
                        v = acc[mi][ni][r] * inv;
                        h[(size_t)row * HID + col] = v;
                        hb[(size_t)row * HID + col] = f2b(v);
                    } else {
                        v = COLSUM ? h[(size_t)row * HID + col] : 0.f;
                    }
                    if (COLSUM) csum[ni] += v;
                }
            }
        }
    if (COLSUM) {
#pragma unroll
        for (int ni = 0; ni < 4; ni++) {
            float p = csum[ni];
            p += __shfl_xor(p, 16);
            p += __shfl_xor(p, 32);
            if (quad == 0) atomicAdd(&s_cs[wcol + ni * 16 + ln15], p);
        }
        __syncthreads();
        if (tid < HID) atomicAdd(&gsumOut[tid], s_cs[tid]);
    }
}

// ---------------- launch ----------------

static inline char* align_up(char* p, size_t a) {
    return (char*)(((uintptr_t)p + a - 1) & ~(uintptr_t)(a - 1));
}

extern "C" void kernel_launch(void* const* d_in, const int* in_sizes, int n_in,
                              void* d_out, int out_size, void* d_ws, size_t ws_size,
                              hipStream_t stream) {
    const float* feat = (const float*)d_in[0];
    const int* src = (const int*)d_in[1];
    const int* dst = (const int*)d_in[2];
    const float* iW0 = (const float*)d_in[3];
    const float* ib0 = (const float*)d_in[4];
    const float* iW1 = (const float*)d_in[5];
    const float* ib1 = (const float*)d_in[6];
    const float* iW2 = (const float*)d_in[7];
    const float* ib2 = (const float*)d_in[8];
    const float* nW0 = (const float*)d_in[9];
    const float* nb0 = (const float*)d_in[10];
    const float* nW1 = (const float*)d_in[11];
    const float* nb1 = (const float*)d_in[12];
    const float* nW2 = (const float*)d_in[13];
    const float* nb2 = (const float*)d_in[14];

    int N = in_sizes[0] / IN_DIM;
    int E = in_sizes[1];
    int n_iter = in_sizes[10] / HID;
    int NB = (N + (1 << NBSH) - 1) >> NBSH;   // 782 for N=50000 (<=1024 assumed in bscan_k)
    float* h = (float*)d_out;

    char* w = (char*)d_ws;
    size_t big2 = (size_t)(N + 64) * HID * sizeof(u16);
    u16* hb   = (u16*)w; w += big2;
    u16* msgb = (u16*)w; w += big2;
    float* gsums = (float*)w; w += (size_t)(n_iter + 1) * HID * sizeof(float);
    u16* Wt = (u16*)w; w += (size_t)(2048 + 2 * 16384 + n_iter * 4 * 16384) * sizeof(u16);
    w = align_up(w, 16);
    int* deg = (int*)w; w += (size_t)N * 4;  w = align_up(w, 16);
    int* row_ptr = (int*)w; w += (size_t)(N + 1) * 4;  w = align_up(w, 16);
    int* cnt = (int*)w; w += (size_t)N * 4;  w = align_up(w, 16);
    int* bktcnt = (int*)w; w += (size_t)NB * 4;  w = align_up(w, 16);
    int* bktbase = (int*)w; w += (size_t)(NB + 1) * 4;  w = align_up(w, 64);
    int* bcnt = (int*)w; w += (size_t)NB * BPAD * 4;  w = align_up(w, 16);
    int* srcs = (int*)w; w += (size_t)E * 4;  w = align_up(w, 16);
    unsigned* ebuf = (unsigned*)w; w += (size_t)E * 4;
    (void)ws_size; (void)n_in; (void)out_size;

    // Wt layout offsets (bf16 elems)
    const int OFF_IW0 = 0;
    const int OFF_IW1 = 2048;
    const int OFF_IW2 = 2048 + 16384;
    const int OFF_IT = 2048 + 2 * 16384;  // per iter: W0a, W0b, W1, W2 (4 x 16384)

    WJobs jobs;
    int nj = 0;
    jobs.src[nj] = iW0; jobs.dstoff[nj] = OFF_IW0; jobs.ks[nj] = 4; nj++;
    jobs.src[nj] = iW1; jobs.dstoff[nj] = OFF_IW1; jobs.ks[nj] = 7; nj++;
    jobs.src[nj] = iW2; jobs.dstoff[nj] = OFF_IW2; jobs.ks[nj] = 7; nj++;
    for (int i = 0; i < n_iter && nj + 4 <= 16; i++) {
        int base = OFF_IT + i * 4 * 16384;
        jobs.src[nj] = nW0 + (size_t)i * 3 * HID * HID;               jobs.dstoff[nj] = base;             jobs.ks[nj] = 7; nj++;
        jobs.src[nj] = nW0 + (size_t)i * 3 * HID * HID + HID * HID;   jobs.dstoff[nj] = base + 16384;     jobs.ks[nj] = 7; nj++;
        jobs.src[nj] = nW1 + (size_t)i * HID * HID;                   jobs.dstoff[nj] = base + 2 * 16384; jobs.ks[nj] = 7; nj++;
        jobs.src[nj] = nW2 + (size_t)i * HID * HID;                   jobs.dstoff[nj] = base + 3 * 16384; jobs.ks[nj] = 7; nj++;
    }

    hipMemsetAsync(deg, 0, (size_t)N * 4, stream);
    hipMemsetAsync(gsums, 0, (size_t)(n_iter + 1) * HID * sizeof(float), stream);

    wprep_k<<<nj, 256, 0, stream>>>(jobs, Wt);

    int eg = (E + 255) / 256;
    count_k<<<eg, 256, 0, stream>>>(dst, deg, E);
    bsum_k<<<NB, 64, 0, stream>>>(deg, bktcnt, N);
    bscan_k<<<1, 1024, 0, stream>>>(bktcnt, bktbase, bcnt, NB, E);
    rptr_k<<<(NB + 3) / 4, 256, 0, stream>>>(deg, bktbase, row_ptr, cnt, N, NB, E);
    bin_k<<<eg, 256, 0, stream>>>(src, dst, bcnt, ebuf, E);
    fill2_k<<<NB, 256, 0, stream>>>(ebuf, bktbase, cnt, srcs, N);

    int gb = (N + 63) / 64;
    int rb = (N + 3) / 4;
    init_fused_k<<<gb, 256, 0, stream>>>(feat, Wt + OFF_IW0, Wt + OFF_IW1, Wt + OFF_IW2,
                                         ib0, ib1, ib2, h, hb, gsums, N);

    for (int i = 0; i < n_iter; i++) {
        const u16* Wit = Wt + OFF_IT + (size_t)i * 4 * 16384;
        const float* Wg = nW0 + (size_t)i * 3 * HID * HID + 2 * HID * HID;
        msg_k<<<rb, 256, 0, stream>>>(hb, row_ptr, srcs, msgb, N);
        if (i + 1 < n_iter) {
            node_fused_k<true><<<gb, 256, 0, stream>>>(msgb, hb, Wit, Wit + 16384, Wit + 2 * 16384,
                                                       Wit + 3 * 16384, nb0 + (size_t)i * HID, Wg,
                                                       gsums + (size_t)i * HID, nb1 + (size_t)i * HID,
                                                       nb2 + (size_t)i * HID, deg, h, hb,
                                                       gsums + (size_t)(i + 1) * HID, N);
        } else {
            node_fused_k<false><<<gb, 256, 0, stream>>>(msgb, hb, Wit, Wit + 16384, Wit + 2 * 16384,
                                                        Wit + 3 * 16384, nb0 + (size_t)i * HID, Wg,
                                                        gsums + (size_t)i * HID, nb1 + (size_t)i * HID,
                                                        nb2 + (size_t)i * HID, deg, h, hb,
                                                        nullptr, N);
        }
    }
}

// Round 9
// 644.081 us; speedup vs baseline: 6.9433x; 1.1294x over previous
//
#include <hip/hip_runtime.h>
#include <hip/hip_bf16.h>

#define HID 128
#define IN_DIM 16
#define LDST 136   // LDS row stride in bf16 elems (272 B)
#define NBSH 6     // bucket = dst >> 6  (64 dsts/bucket)
#define BPAD 16    // bucket counter padding (ints) -> one 64B line per counter
#define SRCM 0x3ffffffu
#define CH 8192    // edges per bin block
#define NBMAX 1024

typedef unsigned short u16;
typedef __attribute__((ext_vector_type(8))) short short8;
typedef __attribute__((ext_vector_type(4))) float f32x4;

__device__ __forceinline__ u16 f2b(float f) {  // RNE
    unsigned u = __float_as_uint(f);
    return (u16)((u + 0x7FFF + ((u >> 16) & 1)) >> 16);
}

// ---------------- graph prep ----------------

__global__ __launch_bounds__(256) void count_k(const int* __restrict__ dst, int* __restrict__ deg, int E) {
    int e = blockIdx.x * 256 + threadIdx.x;
    if (e < E) atomicAdd(&deg[dst[e]], 1);
}

// bucket sums: one wave per bucket of 64 dsts
__global__ __launch_bounds__(64) void bsum_k(const int* __restrict__ deg, int* __restrict__ bktcnt, int n) {
    int b = blockIdx.x;
    int i = (b << NBSH) + threadIdx.x;
    int v = (i < n) ? deg[i] : 0;
#pragma unroll
    for (int off = 1; off < 64; off <<= 1) v += __shfl_xor(v, off);
    if (threadIdx.x == 0) bktcnt[b] = v;
}

// scan bucket sums (nb <= 1024) -> bktbase (exclusive); seed padded bucket counters
__global__ __launch_bounds__(1024) void bscan_k(const int* __restrict__ bktcnt, int* __restrict__ bktbase,
                                                int* __restrict__ bcnt, int nb, int E) {
    __shared__ int sbuf[1024];
    int t = threadIdx.x;
    int v = (t < nb) ? bktcnt[t] : 0;
    sbuf[t] = v;
    __syncthreads();
    for (int off = 1; off < 1024; off <<= 1) {
        int a = (t >= off) ? sbuf[t - off] : 0;
        __syncthreads();
        sbuf[t] += a;
        __syncthreads();
    }
    if (t < nb) {
        int excl = sbuf[t] - v;
        bktbase[t] = excl;
        bcnt[t * BPAD] = excl;
    }
    if (t == 0) bktbase[nb] = E;
}

// per-dst row_ptr from bucket bases: wave per bucket, shuffle prefix over 64 degs; seed cnt
__global__ __launch_bounds__(256) void rptr_k(const int* __restrict__ deg, const int* __restrict__ bktbase,
                                              int* __restrict__ row_ptr, int* __restrict__ cnt,
                                              int n, int nb, int E) {
    int wave = threadIdx.x >> 6, lane = threadIdx.x & 63;
    int b = blockIdx.x * 4 + wave;
    if (b >= nb) return;
    int i = (b << NBSH) + lane;
    int d = (i < n) ? deg[i] : 0;
    int s = d;
#pragma unroll
    for (int off = 1; off < 64; off <<= 1) {
        int t = __shfl_up(s, off);
        if (lane >= off) s += t;
    }
    int rp = bktbase[b] + s - d;  // exclusive
    if (i < n) { row_ptr[i] = rp; cnt[i] = rp; }
    if (i == n - 1) row_ptr[n] = E;
}

// LDS-staged bin: block partitions an 8192-edge chunk by bucket, writes bucket-sorted
// segments (consecutive global addrs within a segment) -> line-merged writebacks.
// Int LDS atomics only (ds_add native).
__global__ __launch_bounds__(256) void bin_k(const int* __restrict__ src, const int* __restrict__ dst,
                                             int* __restrict__ bcnt, unsigned* __restrict__ ebuf,
                                             int E, int nb) {
    __shared__ unsigned stage[CH];   // 32 KB
    __shared__ u16 sbk[CH];          // 16 KB bucket id per slot
    __shared__ int hist[NBMAX];      // 4 KB
    __shared__ int lofs[NBMAX];      // running counters (init = excl scan)
    __shared__ int sbase[NBMAX];     // gbase - excl per bucket
    __shared__ int scan256[256];
    int tid = threadIdx.x;
    int base = blockIdx.x * CH;
    int cnt = E - base; if (cnt > CH) cnt = CH;

    for (int i = tid; i < nb; i += 256) hist[i] = 0;
    __syncthreads();

    // phase 1: histogram (coalesced reads)
    for (int j = tid; j < cnt; j += 256) {
        int d = dst[base + j];
        atomicAdd(&hist[d >> NBSH], 1);
    }
    __syncthreads();

    // phase 2: block scan hist -> excl (lofs); reserve global spans
    int psum[4];
    int ts = 0;
#pragma unroll
    for (int q = 0; q < 4; q++) {
        int idx = tid * 4 + q;
        int hv = (idx < nb) ? hist[idx] : 0;
        psum[q] = ts;
        ts += hv;
    }
    scan256[tid] = ts;
    __syncthreads();
    for (int off = 1; off < 256; off <<= 1) {
        int a = (tid >= off) ? scan256[tid - off] : 0;
        __syncthreads();
        scan256[tid] += a;
        __syncthreads();
    }
    int tbase = (tid > 0) ? scan256[tid - 1] : 0;
#pragma unroll
    for (int q = 0; q < 4; q++) {
        int idx = tid * 4 + q;
        if (idx < nb) lofs[idx] = tbase + psum[q];
    }
    __syncthreads();
    for (int i = tid; i < nb; i += 256) {
        int c = hist[i];
        if (c > 0) {
            int g = atomicAdd(&bcnt[i * BPAD], c);
            sbase[i] = g - lofs[i];
        }
    }
    __syncthreads();

    // phase 3: rank + scatter into LDS staging (bucket-sorted)
    for (int j = tid; j < cnt; j += 256) {
        int e = base + j;
        int d = dst[e];
        int b = d >> NBSH;
        int r = atomicAdd(&lofs[b], 1);
        stage[r] = (unsigned)src[e] | ((unsigned)(d & 63) << 26);
        sbk[r] = (u16)b;
    }
    __syncthreads();

    // phase 4: linear copy-out; same-bucket slots -> consecutive global addrs
    for (int s = tid; s < cnt; s += 256) {
        int b = sbk[s];
        ebuf[sbase[b] + s] = stage[s];
    }
}

// block per bucket: final scatter within small window (block-local writes, L2-merged)
__global__ __launch_bounds__(256) void fill2_k(const unsigned* __restrict__ ebuf, const int* __restrict__ bktbase,
                                               int* __restrict__ cnt, int* __restrict__ srcs, int n) {
    int b = blockIdx.x;
    int e0 = bktbase[b], e1 = bktbase[b + 1];
    int d0 = b << NBSH;
    for (int i = e0 + threadIdx.x; i < e1; i += 256) {
        unsigned p = ebuf[i];
        int d = d0 | (int)(p >> 26);
        int pos = atomicAdd(&cnt[d], 1);
        srcs[pos] = (int)(p & SRCM);
    }
}

// ---------------- weight prep: fp32 [K,128] -> bf16 [128][K] (n-major) ----------------

struct WJobs {
    const float* src[16];
    int dstoff[16];
    int ks[16];  // log2 K
};

__global__ __launch_bounds__(256) void wprep_k(WJobs j, u16* __restrict__ Wt) {
    int m = blockIdx.x;
    const float* s = j.src[m];
    u16* d = Wt + j.dstoff[m];
    int ks = j.ks[m];
    int K = 1 << ks;
    int tot = K * HID;
    for (int idx = threadIdx.x; idx < tot; idx += 256) {
        int nn = idx >> ks;
        int kk = idx & (K - 1);
        d[idx] = f2b(s[kk * HID + nn]);
    }
}

// ---------------- message aggregation: gather bf16 h rows, wave per dst (CSR) ----------------

__global__ __launch_bounds__(256) void msg_k(const u16* __restrict__ hb, const int* __restrict__ row_ptr,
                                             const int* __restrict__ srcs, u16* __restrict__ msgb, int n) {
    int wave = threadIdx.x >> 6, lane = threadIdx.x & 63;
    int d = blockIdx.x * 4 + wave;
    if (d >= n) return;
    int e = row_ptr[d], e1 = row_ptr[d + 1];
    float a0 = 0.f, a1 = 0.f;
    for (; e + 3 < e1; e += 4) {
        int s0 = srcs[e], s1 = srcs[e + 1], s2 = srcs[e + 2], s3 = srcs[e + 3];
        unsigned v0 = *(const unsigned*)(hb + (size_t)s0 * HID + lane * 2);
        unsigned v1 = *(const unsigned*)(hb + (size_t)s1 * HID + lane * 2);
        unsigned v2 = *(const unsigned*)(hb + (size_t)s2 * HID + lane * 2);
        unsigned v3 = *(const unsigned*)(hb + (size_t)s3 * HID + lane * 2);
        a0 += __uint_as_float(v0 << 16) + __uint_as_float(v1 << 16) +
              __uint_as_float(v2 << 16) + __uint_as_float(v3 << 16);
        a1 += __uint_as_float(v0 & 0xffff0000u) + __uint_as_float(v1 & 0xffff0000u) +
              __uint_as_float(v2 & 0xffff0000u) + __uint_as_float(v3 & 0xffff0000u);
    }
    for (; e < e1; e++) {
        unsigned v = *(const unsigned*)(hb + (size_t)srcs[e] * HID + lane * 2);
        a0 += __uint_as_float(v << 16);
        a1 += __uint_as_float(v & 0xffff0000u);
    }
    unsigned out = (unsigned)f2b(a0) | ((unsigned)f2b(a1) << 16);
    *(unsigned*)(msgb + (size_t)d * HID + lane * 2) = out;
}

// ---------------- MFMA building blocks: 64x128 C-tile, 4 waves (2x2), 16x16x32 bf16 ----------------

__device__ __forceinline__ void stageA128(const u16* __restrict__ A, int row0, int tid, u16* sA) {
#pragma unroll
    for (int q = 0; q < 4; q++) {
        int c = tid + q * 256;
        int row = c >> 4, j8 = c & 15;
        uint4 v = *(const uint4*)(A + (size_t)(row0 + row) * HID + j8 * 8);
        *(uint4*)(sA + row * LDST + j8 * 8) = v;
    }
}

__device__ __forceinline__ void stageW128(const u16* __restrict__ Wt, int tid, u16* sB) {
#pragma unroll
    for (int q = 0; q < 8; q++) {
        int c = tid + q * 256;
        int row = c >> 4, j8 = c & 15;
        uint4 v = *(const uint4*)(Wt + row * HID + j8 * 8);
        *(uint4*)(sB + row * LDST + j8 * 8) = v;
    }
}

__device__ __forceinline__ void stageFeat(const float* __restrict__ feat, int row0, int n, int tid, u16* sA) {
    int row = tid >> 2, coff = tid & 3;
    ushort4 o = make_ushort4(0, 0, 0, 0);
    if (row0 + row < n) {
        float4 v = *(const float4*)(feat + (size_t)(row0 + row) * IN_DIM + coff * 4);
        o = make_ushort4(f2b(v.x), f2b(v.y), f2b(v.z), f2b(v.w));
    }
    *(ushort4*)(sA + row * LDST + coff * 4) = o;
    *(ushort4*)(sA + row * LDST + 16 + coff * 4) = make_ushort4(0, 0, 0, 0);  // zero-pad K 16->32
}

__device__ __forceinline__ void stageW16(const u16* __restrict__ Wt, int tid, u16* sB) {
    int row = tid >> 1, h8 = tid & 1;
    uint4 v = *(const uint4*)(Wt + row * IN_DIM + h8 * 8);
    *(uint4*)(sB + row * LDST + h8 * 8) = v;
    *(uint4*)(sB + row * LDST + 16 + h8 * 8) = make_uint4(0, 0, 0, 0);
}

template <int KSTEPS>
__device__ __forceinline__ void mac(const u16* sA, const u16* sB, int wrow, int wcol,
                                    int ln15, int quad, f32x4 acc[2][4]) {
#pragma unroll
    for (int kk = 0; kk < KSTEPS; kk++) {
        short8 a[2], b[4];
#pragma unroll
        for (int mi = 0; mi < 2; mi++)
            a[mi] = *(const short8*)(sA + (wrow + mi * 16 + ln15) * LDST + kk * 32 + quad * 8);
#pragma unroll
        for (int ni = 0; ni < 4; ni++)
            b[ni] = *(const short8*)(sB + (wcol + ni * 16 + ln15) * LDST + kk * 32 + quad * 8);
#pragma unroll
        for (int mi = 0; mi < 2; mi++)
#pragma unroll
            for (int ni = 0; ni < 4; ni++)
                acc[mi][ni] = __builtin_amdgcn_mfma_f32_16x16x32_bf16(a[mi], b[ni], acc[mi][ni], 0, 0, 0);
    }
}

__device__ __forceinline__ void set_bias(f32x4 acc[2][4], const float* __restrict__ bias, int wcol, int ln15) {
#pragma unroll
    for (int ni = 0; ni < 4; ni++) {
        float bv = bias[wcol + ni * 16 + ln15];
#pragma unroll
        for (int mi = 0; mi < 2; mi++) acc[mi][ni] = (f32x4){bv, bv, bv, bv};
    }
}

// relu(acc) -> sA in [row][col] layout (== next layer's A-operand layout)
__device__ __forceinline__ void acc_to_sA(const f32x4 acc[2][4], u16* sA, int wrow, int wcol,
                                          int ln15, int quad) {
#pragma unroll
    for (int mi = 0; mi < 2; mi++)
#pragma unroll
        for (int r = 0; r < 4; r++) {
            int row = wrow + mi * 16 + quad * 4 + r;
#pragma unroll
            for (int ni = 0; ni < 4; ni++)
                sA[row * LDST + wcol + ni * 16 + ln15] = f2b(fmaxf(acc[mi][ni][r], 0.f));
        }
}

// ---------------- fused init MLP: feat -> relu -> relu -> h (+hb) + colsum ----------------

__global__ __launch_bounds__(256, 3) void init_fused_k(const float* __restrict__ feat,
                                                       const u16* __restrict__ W0t, const u16* __restrict__ W1t,
                                                       const u16* __restrict__ W2t,
                                                       const float* __restrict__ b0, const float* __restrict__ b1,
                                                       const float* __restrict__ b2,
                                                       float* __restrict__ h, u16* __restrict__ hb,
                                                       float* __restrict__ gsum0, int n) {
    __shared__ u16 sA[64 * LDST];
    __shared__ u16 sB[128 * LDST];
    int tid = threadIdx.x;
    int lane = tid & 63, wave = tid >> 6;
    int ln15 = lane & 15, quad = lane >> 4;
    int wrow = (wave >> 1) * 32, wcol = (wave & 1) * 64;
    int row0 = blockIdx.x * 64;
    f32x4 acc[2][4];

    stageFeat(feat, row0, n, tid, sA);
    stageW16(W0t, tid, sB);
    set_bias(acc, b0, wcol, ln15);
    __syncthreads();
    mac<1>(sA, sB, wrow, wcol, ln15, quad, acc);
    __syncthreads();
    acc_to_sA(acc, sA, wrow, wcol, ln15, quad);
    stageW128(W1t, tid, sB);
    set_bias(acc, b1, wcol, ln15);
    __syncthreads();
    mac<4>(sA, sB, wrow, wcol, ln15, quad, acc);
    __syncthreads();
    acc_to_sA(acc, sA, wrow, wcol, ln15, quad);
    stageW128(W2t, tid, sB);
    set_bias(acc, b2, wcol, ln15);
    __syncthreads();
    mac<4>(sA, sB, wrow, wcol, ln15, quad, acc);

    float csum[4] = {0.f, 0.f, 0.f, 0.f};
#pragma unroll
    for (int mi = 0; mi < 2; mi++)
#pragma unroll
        for (int r = 0; r < 4; r++) {
            int row = row0 + wrow + mi * 16 + quad * 4 + r;
            if (row < n) {
#pragma unroll
                for (int ni = 0; ni < 4; ni++) {
                    float v = acc[mi][ni][r];
                    int col = wcol + ni * 16 + ln15;
                    h[(size_t)row * HID + col] = v;
                    hb[(size_t)row * HID + col] = f2b(v);
                    csum[ni] += v;
                }
            }
        }
    __syncthreads();
    float* s_cs = (float*)sA;
    if (tid < HID) s_cs[tid] = 0.f;
    __syncthreads();
#pragma unroll
    for (int ni = 0; ni < 4; ni++) {
        float p = csum[ni];
        p += __shfl_xor(p, 16);
        p += __shfl_xor(p, 32);
        if (quad == 0) atomicAdd(&s_cs[wcol + ni * 16 + ln15], p);
    }
    __syncthreads();
    if (tid < HID) atomicAdd(&gsum0[tid], s_cs[tid]);
}

// ---------------- fused node update ----------------

template <bool COLSUM>
__global__ __launch_bounds__(256, 3) void node_fused_k(const u16* __restrict__ msgb, const u16* __restrict__ hbin,
                                                       const u16* __restrict__ W0a, const u16* __restrict__ W0b,
                                                       const u16* __restrict__ W1t, const u16* __restrict__ W2t,
                                                       const float* __restrict__ b0, const float* __restrict__ Wg,
                                                       const float* __restrict__ gsumIn,
                                                       const float* __restrict__ b1, const float* __restrict__ b2,
                                                       const int* __restrict__ deg,
                                                       float* __restrict__ h, u16* __restrict__ hb,
                                                       float* __restrict__ gsumOut, int n) {
    __shared__ u16 sA[64 * LDST];
    __shared__ u16 sB[128 * LDST];
    __shared__ float s_gr[HID];
    __shared__ float s_grW[HID];
    __shared__ float s_red[2];
    int tid = threadIdx.x;
    int lane = tid & 63, wave = tid >> 6;
    int ln15 = lane & 15, quad = lane >> 4;
    int wrow = (wave >> 1) * 32, wcol = (wave & 1) * 64;
    int row0 = blockIdx.x * 64;
    f32x4 acc[2][4];

    stageA128(msgb, row0, tid, sA);
    stageW128(W0a, tid, sB);
    if (tid < HID) {
        float g = gsumIn[tid];
        float s = g * g;
#pragma unroll
        for (int off = 1; off < 64; off <<= 1) s += __shfl_xor(s, off);
        if ((tid & 63) == 0) s_red[tid >> 6] = s;
    }
    __syncthreads();
    if (tid < HID) {
        float inv = 1.f / (sqrtf(s_red[0] + s_red[1]) + 1e-8f);
        s_gr[tid] = gsumIn[tid] * inv;
    }
    __syncthreads();
    if (tid < HID) {
        float a = b0[tid];
#pragma unroll 4
        for (int k = 0; k < HID; k++) a += s_gr[k] * Wg[k * HID + tid];
        s_grW[tid] = a;
    }
    __syncthreads();
    set_bias(acc, s_grW, wcol, ln15);
    mac<4>(sA, sB, wrow, wcol, ln15, quad, acc);     // msg @ W0a
    __syncthreads();
    stageA128(hbin, row0, tid, sA);
    stageW128(W0b, tid, sB);
    __syncthreads();
    mac<4>(sA, sB, wrow, wcol, ln15, quad, acc);     // + h @ W0b
    __syncthreads();
    acc_to_sA(acc, sA, wrow, wcol, ln15, quad);
    stageW128(W1t, tid, sB);
    set_bias(acc, b1, wcol, ln15);
    __syncthreads();
    mac<4>(sA, sB, wrow, wcol, ln15, quad, acc);
    __syncthreads();
    acc_to_sA(acc, sA, wrow, wcol, ln15, quad);
    stageW128(W2t, tid, sB);
    set_bias(acc, b2, wcol, ln15);
    __syncthreads();
    mac<4>(sA, sB, wrow, wcol, ln15, quad, acc);

    __syncthreads();
    float* s_rs = (float*)sA;             // [64] row sum-of-squares
    float* s_cs = (float*)sA + 64;        // [128] col sums
    if (tid < 64) s_rs[tid] = 0.f;
    else if (tid < 192) s_cs[tid - 64] = 0.f;
    __syncthreads();
#pragma unroll
    for (int mi = 0; mi < 2; mi++)
#pragma unroll
        for (int r = 0; r < 4; r++) {
            float p = 0.f;
#pragma unroll
            for (int ni = 0; ni < 4; ni++) { float v = acc[mi][ni][r]; p += v * v; }
            p += __shfl_xor(p, 1); p += __shfl_xor(p, 2);
            p += __shfl_xor(p, 4); p += __shfl_xor(p, 8);
            if (ln15 == 0) atomicAdd(&s_rs[wrow + mi * 16 + quad * 4 + r], p);
        }
    __syncthreads();
    float csum[4] = {0.f, 0.f, 0.f, 0.f};
#pragma unroll
    for (int mi = 0; mi < 2; mi++)
#pragma unroll
        for (int r = 0; r < 4; r++) {
            int rl = wrow + mi * 16 + quad * 4 + r;
            int row = row0 + rl;
            if (row < n) {
                bool upd = deg[row] > 0;
                float inv = 1.f / (sqrtf(s_rs[rl]) + 1e-8f);
#pragma unroll
                for (int ni = 0; ni < 4; ni++) {
                    int col = wcol + ni * 16 + ln15;
                    float v;
                    if (upd) {
                        v = acc[mi][ni][r] * inv;
                        h[(size_t)row * HID + col] = v;
                        hb[(size_t)row * HID + col] = f2b(v);
                    } else {
                        v = COLSUM ? h[(size_t)row * HID + col] : 0.f;
                    }
                    if (COLSUM) csum[ni] += v;
                }
            }
        }
    if (COLSUM) {
#pragma unroll
        for (int ni = 0; ni < 4; ni++) {
            float p = csum[ni];
            p += __shfl_xor(p, 16);
            p += __shfl_xor(p, 32);
            if (quad == 0) atomicAdd(&s_cs[wcol + ni * 16 + ln15], p);
        }
        __syncthreads();
        if (tid < HID) atomicAdd(&gsumOut[tid], s_cs[tid]);
    }
}

// ---------------- launch ----------------

static inline char* align_up(char* p, size_t a) {
    return (char*)(((uintptr_t)p + a - 1) & ~(uintptr_t)(a - 1));
}

extern "C" void kernel_launch(void* const* d_in, const int* in_sizes, int n_in,
                              void* d_out, int out_size, void* d_ws, size_t ws_size,
                              hipStream_t stream) {
    const float* feat = (const float*)d_in[0];
    const int* src = (const int*)d_in[1];
    const int* dst = (const int*)d_in[2];
    const float* iW0 = (const float*)d_in[3];
    const float* ib0 = (const float*)d_in[4];
    const float* iW1 = (const float*)d_in[5];
    const float* ib1 = (const float*)d_in[6];
    const float* iW2 = (const float*)d_in[7];
    const float* ib2 = (const float*)d_in[8];
    const float* nW0 = (const float*)d_in[9];
    const float* nb0 = (const float*)d_in[10];
    const float* nW1 = (const float*)d_in[11];
    const float* nb1 = (const float*)d_in[12];
    const float* nW2 = (const float*)d_in[13];
    const float* nb2 = (const float*)d_in[14];

    int N = in_sizes[0] / IN_DIM;
    int E = in_sizes[1];
    int n_iter = in_sizes[10] / HID;
    int NB = (N + (1 << NBSH) - 1) >> NBSH;   // 782 for N=50000 (<=1024 assumed)
    float* h = (float*)d_out;

    char* w = (char*)d_ws;
    size_t big2 = (size_t)(N + 64) * HID * sizeof(u16);
    u16* hb   = (u16*)w; w += big2;
    u16* msgb = (u16*)w; w += big2;
    float* gsums = (float*)w; w += (size_t)(n_iter + 1) * HID * sizeof(float);
    u16* Wt = (u16*)w; w += (size_t)(2048 + 2 * 16384 + n_iter * 4 * 16384) * sizeof(u16);
    w = align_up(w, 16);
    int* deg = (int*)w; w += (size_t)N * 4;  w = align_up(w, 16);
    int* row_ptr = (int*)w; w += (size_t)(N + 1) * 4;  w = align_up(w, 16);
    int* cnt = (int*)w; w += (size_t)N * 4;  w = align_up(w, 16);
    int* bktcnt = (int*)w; w += (size_t)NB * 4;  w = align_up(w, 16);
    int* bktbase = (int*)w; w += (size_t)(NB + 1) * 4;  w = align_up(w, 64);
    int* bcnt = (int*)w; w += (size_t)NB * BPAD * 4;  w = align_up(w, 16);
    int* srcs = (int*)w; w += (size_t)E * 4;  w = align_up(w, 16);
    unsigned* ebuf = (unsigned*)w; w += (size_t)E * 4;
    (void)ws_size; (void)n_in; (void)out_size;

    // Wt layout offsets (bf16 elems)
    const int OFF_IW0 = 0;
    const int OFF_IW1 = 2048;
    const int OFF_IW2 = 2048 + 16384;
    const int OFF_IT = 2048 + 2 * 16384;  // per iter: W0a, W0b, W1, W2 (4 x 16384)

    WJobs jobs;
    int nj = 0;
    jobs.src[nj] = iW0; jobs.dstoff[nj] = OFF_IW0; jobs.ks[nj] = 4; nj++;
    jobs.src[nj] = iW1; jobs.dstoff[nj] = OFF_IW1; jobs.ks[nj] = 7; nj++;
    jobs.src[nj] = iW2; jobs.dstoff[nj] = OFF_IW2; jobs.ks[nj] = 7; nj++;
    for (int i = 0; i < n_iter && nj + 4 <= 16; i++) {
        int base = OFF_IT + i * 4 * 16384;
        jobs.src[nj] = nW0 + (size_t)i * 3 * HID * HID;               jobs.dstoff[nj] = base;             jobs.ks[nj] = 7; nj++;
        jobs.src[nj] = nW0 + (size_t)i * 3 * HID * HID + HID * HID;   jobs.dstoff[nj] = base + 16384;     jobs.ks[nj] = 7; nj++;
        jobs.src[nj] = nW1 + (size_t)i * HID * HID;                   jobs.dstoff[nj] = base + 2 * 16384; jobs.ks[nj] = 7; nj++;
        jobs.src[nj] = nW2 + (size_t)i * HID * HID;                   jobs.dstoff[nj] = base + 3 * 16384; jobs.ks[nj] = 7; nj++;
    }

    hipMemsetAsync(deg, 0, (size_t)N * 4, stream);
    hipMemsetAsync(gsums, 0, (size_t)(n_iter + 1) * HID * sizeof(float), stream);

    wprep_k<<<nj, 256, 0, stream>>>(jobs, Wt);

    int eg = (E + 255) / 256;
    count_k<<<eg, 256, 0, stream>>>(dst, deg, E);
    bsum_k<<<NB, 64, 0, stream>>>(deg, bktcnt, N);
    bscan_k<<<1, 1024, 0, stream>>>(bktcnt, bktbase, bcnt, NB, E);
    rptr_k<<<(NB + 3) / 4, 256, 0, stream>>>(deg, bktbase, row_ptr, cnt, N, NB, E);
    bin_k<<<(E + CH - 1) / CH, 256, 0, stream>>>(src, dst, bcnt, ebuf, E, NB);
    fill2_k<<<NB, 256, 0, stream>>>(ebuf, bktbase, cnt, srcs, N);

    int gb = (N + 63) / 64;
    int rb = (N + 3) / 4;
    init_fused_k<<<gb, 256, 0, stream>>>(feat, Wt + OFF_IW0, Wt + OFF_IW1, Wt + OFF_IW2,
                                         ib0, ib1, ib2, h, hb, gsums, N);

    for (int i = 0; i < n_iter; i++) {
        const u16* Wit = Wt + OFF_IT + (size_t)i * 4 * 16384;
        const float* Wg = nW0 + (size_t)i * 3 * HID * HID + 2 * HID * HID;
        msg_k<<<rb, 256, 0, stream>>>(hb, row_ptr, srcs, msgb, N);
        if (i + 1 < n_iter) {
            node_fused_k<true><<<gb, 256, 0, stream>>>(msgb, hb, Wit, Wit + 16384, Wit + 2 * 16384,
                                                       Wit + 3 * 16384, nb0 + (size_t)i * HID, Wg,
                                                       gsums + (size_t)i * HID, nb1 + (size_t)i * HID,
                                                       nb2 + (size_t)i * HID, deg, h, hb,
                                                       gsums + (size_t)(i + 1) * HID, N);
        } else {
            node_fused_k<false><<<gb, 256, 0, stream>>>(msgb, hb, Wit, Wit + 16384, Wit + 2 * 16384,
                                                        Wit + 3 * 16384, nb0 + (size_t)i * HID, Wg,
                                                        gsums + (size_t)i * HID, nb1 + (size_t)i * HID,
                                                        nb2 + (size_t)i * HID, deg, h, hb,
                                                        nullptr, N);
        }
    }
}

// Round 10
// 532.089 us; speedup vs baseline: 8.4047x; 1.2105x over previous
//
#include <hip/hip_runtime.h>
#include <hip/hip_bf16.h>

#define HID 128
#define IN_DIM 16
#define LDST 136   // LDS row stride in bf16 elems (272 B)
#define NBSH 6     // bucket = dst >> 6  (64 dsts/bucket)
#define BPAD 16    // bucket counter padding (ints) -> one 64B line per counter
#define SRCM 0x3ffffffu
#define CH 8192    // edges per chunk (hist_k / bin_k)
#define NBMAX 1024

typedef unsigned short u16;
typedef __attribute__((ext_vector_type(8))) short short8;
typedef __attribute__((ext_vector_type(4))) float f32x4;

__device__ __forceinline__ u16 f2b(float f) {  // RNE
    unsigned u = __float_as_uint(f);
    return (u16)((u + 0x7FFF + ((u >> 16) & 1)) >> 16);
}

// ---------------- graph prep ----------------
// Lesson (r9): E-scale scattered global atomics write through at ~32B/atomic (~50MB HBM).
// All per-edge counting is done in LDS; global atomics only at block x bucket granularity.

// bucket-level histogram via LDS (replaces count_k+bsum_k)
__global__ __launch_bounds__(256) void hist_k(const int* __restrict__ dst, int* __restrict__ bktcnt,
                                              int E, int nb) {
    __shared__ int hist[NBMAX];
    int tid = threadIdx.x;
    int base = blockIdx.x * CH;
    int cnt = E - base; if (cnt > CH) cnt = CH;
    for (int i = tid; i < nb; i += 256) hist[i] = 0;
    __syncthreads();
    for (int j = tid; j < cnt; j += 256) atomicAdd(&hist[dst[base + j] >> NBSH], 1);
    __syncthreads();
    for (int i = tid; i < nb; i += 256) {
        int c = hist[i];
        if (c > 0) atomicAdd(&bktcnt[i], c);
    }
}

// scan bucket sums (nb <= 1024) -> bktbase (exclusive); seed padded bucket counters; row_ptr[n]=E
__global__ __launch_bounds__(1024) void bscan_k(const int* __restrict__ bktcnt, int* __restrict__ bktbase,
                                                int* __restrict__ bcnt, int* __restrict__ row_ptr,
                                                int nb, int n, int E) {
    __shared__ int sbuf[1024];
    int t = threadIdx.x;
    int v = (t < nb) ? bktcnt[t] : 0;
    sbuf[t] = v;
    __syncthreads();
    for (int off = 1; off < 1024; off <<= 1) {
        int a = (t >= off) ? sbuf[t - off] : 0;
        __syncthreads();
        sbuf[t] += a;
        __syncthreads();
    }
    if (t < nb) {
        int excl = sbuf[t] - v;
        bktbase[t] = excl;
        bcnt[t * BPAD] = excl;
    }
    if (t == 0) { bktbase[nb] = E; row_ptr[n] = E; }
}

// LDS-staged bin: block partitions an 8192-edge chunk by bucket, writes bucket-sorted
// segments (consecutive global addrs within a segment) -> line-merged writebacks.
__global__ __launch_bounds__(256) void bin_k(const int* __restrict__ src, const int* __restrict__ dst,
                                             int* __restrict__ bcnt, unsigned* __restrict__ ebuf,
                                             int E, int nb) {
    __shared__ unsigned stage[CH];   // 32 KB
    __shared__ u16 sbk[CH];          // 16 KB bucket id per slot
    __shared__ int hist[NBMAX];      // 4 KB
    __shared__ int lofs[NBMAX];
    __shared__ int sbase[NBMAX];
    __shared__ int scan256[256];
    int tid = threadIdx.x;
    int base = blockIdx.x * CH;
    int cnt = E - base; if (cnt > CH) cnt = CH;

    for (int i = tid; i < nb; i += 256) hist[i] = 0;
    __syncthreads();

    for (int j = tid; j < cnt; j += 256) {
        int d = dst[base + j];
        atomicAdd(&hist[d >> NBSH], 1);
    }
    __syncthreads();

    int psum[4];
    int ts = 0;
#pragma unroll
    for (int q = 0; q < 4; q++) {
        int idx = tid * 4 + q;
        int hv = (idx < nb) ? hist[idx] : 0;
        psum[q] = ts;
        ts += hv;
    }
    scan256[tid] = ts;
    __syncthreads();
    for (int off = 1; off < 256; off <<= 1) {
        int a = (tid >= off) ? scan256[tid - off] : 0;
        __syncthreads();
        scan256[tid] += a;
        __syncthreads();
    }
    int tbase = (tid > 0) ? scan256[tid - 1] : 0;
#pragma unroll
    for (int q = 0; q < 4; q++) {
        int idx = tid * 4 + q;
        if (idx < nb) lofs[idx] = tbase + psum[q];
    }
    __syncthreads();
    for (int i = tid; i < nb; i += 256) {
        int c = hist[i];
        if (c > 0) {
            int g = atomicAdd(&bcnt[i * BPAD], c);
            sbase[i] = g - lofs[i];
        }
    }
    __syncthreads();

    for (int j = tid; j < cnt; j += 256) {
        int e = base + j;
        int d = dst[e];
        int b = d >> NBSH;
        int r = atomicAdd(&lofs[b], 1);
        stage[r] = (unsigned)src[e] | ((unsigned)(d & 63) << 26);
        sbk[r] = (u16)b;
    }
    __syncthreads();

    for (int s = tid; s < cnt; s += 256) {
        int b = sbk[s];
        ebuf[sbase[b] + s] = stage[s];
    }
}

// block per bucket: per-dst histogram/prefix in LDS -> row_ptr + deg + rank-scatter srcs
// (replaces rptr_k + old fill2_k; no global per-dst atomics)
__global__ __launch_bounds__(256) void fill2_k(const unsigned* __restrict__ ebuf, const int* __restrict__ bktbase,
                                               int* __restrict__ row_ptr, int* __restrict__ deg,
                                               int* __restrict__ srcs, int n) {
    __shared__ int hist64[64];
    __shared__ int lofs[64];
    int tid = threadIdx.x;
    int b = blockIdx.x;
    int e0 = bktbase[b], e1 = bktbase[b + 1];
    if (tid < 64) hist64[tid] = 0;
    __syncthreads();
    for (int i = e0 + tid; i < e1; i += 256) atomicAdd(&hist64[ebuf[i] >> 26], 1);
    __syncthreads();
    if (tid < 64) {  // wave 0: prefix over 64 dst counts
        int d = hist64[tid];
        int s = d;
#pragma unroll
        for (int off = 1; off < 64; off <<= 1) {
            int t = __shfl_up(s, off);
            if (tid >= off) s += t;
        }
        int excl = e0 + s - d;
        int gi = (b << NBSH) + tid;
        if (gi < n) { row_ptr[gi] = excl; deg[gi] = d; }
        lofs[tid] = excl;
    }
    __syncthreads();
    for (int i = e0 + tid; i < e1; i += 256) {
        unsigned p = ebuf[i];
        int d = (int)(p >> 26);
        int pos = atomicAdd(&lofs[d], 1);
        srcs[pos] = (int)(p & SRCM);
    }
}

// ---------------- weight prep: fp32 [K,128] -> bf16 [128][K] (n-major) ----------------

struct WJobs {
    const float* src[16];
    int dstoff[16];
    int ks[16];  // log2 K
};

__global__ __launch_bounds__(256) void wprep_k(WJobs j, u16* __restrict__ Wt) {
    int m = blockIdx.x;
    const float* s = j.src[m];
    u16* d = Wt + j.dstoff[m];
    int ks = j.ks[m];
    int K = 1 << ks;
    int tot = K * HID;
    for (int idx = threadIdx.x; idx < tot; idx += 256) {
        int nn = idx >> ks;
        int kk = idx & (K - 1);
        d[idx] = f2b(s[kk * HID + nn]);
    }
}

// ---------------- message aggregation: gather bf16 h rows, wave per dst (CSR) ----------------

__global__ __launch_bounds__(256) void msg_k(const u16* __restrict__ hb, const int* __restrict__ row_ptr,
                                             const int* __restrict__ srcs, u16* __restrict__ msgb, int n) {
    int wave = threadIdx.x >> 6, lane = threadIdx.x & 63;
    int d = blockIdx.x * 4 + wave;
    if (d >= n) return;
    int e = row_ptr[d], e1 = row_ptr[d + 1];
    float a0 = 0.f, a1 = 0.f;
    for (; e + 3 < e1; e += 4) {
        int s0 = srcs[e], s1 = srcs[e + 1], s2 = srcs[e + 2], s3 = srcs[e + 3];
        unsigned v0 = *(const unsigned*)(hb + (size_t)s0 * HID + lane * 2);
        unsigned v1 = *(const unsigned*)(hb + (size_t)s1 * HID + lane * 2);
        unsigned v2 = *(const unsigned*)(hb + (size_t)s2 * HID + lane * 2);
        unsigned v3 = *(const unsigned*)(hb + (size_t)s3 * HID + lane * 2);
        a0 += __uint_as_float(v0 << 16) + __uint_as_float(v1 << 16) +
              __uint_as_float(v2 << 16) + __uint_as_float(v3 << 16);
        a1 += __uint_as_float(v0 & 0xffff0000u) + __uint_as_float(v1 & 0xffff0000u) +
              __uint_as_float(v2 & 0xffff0000u) + __uint_as_float(v3 & 0xffff0000u);
    }
    for (; e < e1; e++) {
        unsigned v = *(const unsigned*)(hb + (size_t)srcs[e] * HID + lane * 2);
        a0 += __uint_as_float(v << 16);
        a1 += __uint_as_float(v & 0xffff0000u);
    }
    unsigned out = (unsigned)f2b(a0) | ((unsigned)f2b(a1) << 16);
    *(unsigned*)(msgb + (size_t)d * HID + lane * 2) = out;
}

// ---------------- MFMA building blocks: 64x128 C-tile, 4 waves (2x2), 16x16x32 bf16 ----------------

__device__ __forceinline__ void stageA128(const u16* __restrict__ A, int row0, int tid, u16* sA) {
#pragma unroll
    for (int q = 0; q < 4; q++) {
        int c = tid + q * 256;
        int row = c >> 4, j8 = c & 15;
        uint4 v = *(const uint4*)(A + (size_t)(row0 + row) * HID + j8 * 8);
        *(uint4*)(sA + row * LDST + j8 * 8) = v;
    }
}

__device__ __forceinline__ void stageW128(const u16* __restrict__ Wt, int tid, u16* sB) {
#pragma unroll
    for (int q = 0; q < 8; q++) {
        int c = tid + q * 256;
        int row = c >> 4, j8 = c & 15;
        uint4 v = *(const uint4*)(Wt + row * HID + j8 * 8);
        *(uint4*)(sB + row * LDST + j8 * 8) = v;
    }
}

__device__ __forceinline__ void stageFeat(const float* __restrict__ feat, int row0, int n, int tid, u16* sA) {
    int row = tid >> 2, coff = tid & 3;
    ushort4 o = make_ushort4(0, 0, 0, 0);
    if (row0 + row < n) {
        float4 v = *(const float4*)(feat + (size_t)(row0 + row) * IN_DIM + coff * 4);
        o = make_ushort4(f2b(v.x), f2b(v.y), f2b(v.z), f2b(v.w));
    }
    *(ushort4*)(sA + row * LDST + coff * 4) = o;
    *(ushort4*)(sA + row * LDST + 16 + coff * 4) = make_ushort4(0, 0, 0, 0);  // zero-pad K 16->32
}

__device__ __forceinline__ void stageW16(const u16* __restrict__ Wt, int tid, u16* sB) {
    int row = tid >> 1, h8 = tid & 1;
    uint4 v = *(const uint4*)(Wt + row * IN_DIM + h8 * 8);
    *(uint4*)(sB + row * LDST + h8 * 8) = v;
    *(uint4*)(sB + row * LDST + 16 + h8 * 8) = make_uint4(0, 0, 0, 0);
}

template <int KSTEPS>
__device__ __forceinline__ void mac(const u16* sA, const u16* sB, int wrow, int wcol,
                                    int ln15, int quad, f32x4 acc[2][4]) {
#pragma unroll
    for (int kk = 0; kk < KSTEPS; kk++) {
        short8 a[2], b[4];
#pragma unroll
        for (int mi = 0; mi < 2; mi++)
            a[mi] = *(const short8*)(sA + (wrow + mi * 16 + ln15) * LDST + kk * 32 + quad * 8);
#pragma unroll
        for (int ni = 0; ni < 4; ni++)
            b[ni] = *(const short8*)(sB + (wcol + ni * 16 + ln15) * LDST + kk * 32 + quad * 8);
#pragma unroll
        for (int mi = 0; mi < 2; mi++)
#pragma unroll
            for (int ni = 0; ni < 4; ni++)
                acc[mi][ni] = __builtin_amdgcn_mfma_f32_16x16x32_bf16(a[mi], b[ni], acc[mi][ni], 0, 0, 0);
    }
}

__device__ __forceinline__ void set_bias(f32x4 acc[2][4], const float* __restrict__ bias, int wcol, int ln15) {
#pragma unroll
    for (int ni = 0; ni < 4; ni++) {
        float bv = bias[wcol + ni * 16 + ln15];
#pragma unroll
        for (int mi = 0; mi < 2; mi++) acc[mi][ni] = (f32x4){bv, bv, bv, bv};
    }
}

// relu(acc) -> sA in [row][col] layout (== next layer's A-operand layout)
__device__ __forceinline__ void acc_to_sA(const f32x4 acc[2][4], u16* sA, int wrow, int wcol,
                                          int ln15, int quad) {
#pragma unroll
    for (int mi = 0; mi < 2; mi++)
#pragma unroll
        for (int r = 0; r < 4; r++) {
            int row = wrow + mi * 16 + quad * 4 + r;
#pragma unroll
            for (int ni = 0; ni < 4; ni++)
                sA[row * LDST + wcol + ni * 16 + ln15] = f2b(fmaxf(acc[mi][ni][r], 0.f));
        }
}

// ---------------- fused init MLP: feat -> relu -> relu -> h (+hb) + colsum ----------------

__global__ __launch_bounds__(256, 3) void init_fused_k(const float* __restrict__ feat,
                                                       const u16* __restrict__ W0t, const u16* __restrict__ W1t,
                                                       const u16* __restrict__ W2t,
                                                       const float* __restrict__ b0, const float* __restrict__ b1,
                                                       const float* __restrict__ b2,
                                                       float* __restrict__ h, u16* __restrict__ hb,
                                                       float* __restrict__ gsum0, int n) {
    __shared__ u16 sA[64 * LDST];
    __shared__ u16 sB[128 * LDST];
    int tid = threadIdx.x;
    int lane = tid & 63, wave = tid >> 6;
    int ln15 = lane & 15, quad = lane >> 4;
    int wrow = (wave >> 1) * 32, wcol = (wave & 1) * 64;
    int row0 = blockIdx.x * 64;
    f32x4 acc[2][4];

    stageFeat(feat, row0, n, tid, sA);
    stageW16(W0t, tid, sB);
    set_bias(acc, b0, wcol, ln15);
    __syncthreads();
    mac<1>(sA, sB, wrow, wcol, ln15, quad, acc);
    __syncthreads();
    acc_to_sA(acc, sA, wrow, wcol, ln15, quad);
    stageW128(W1t, tid, sB);
    set_bias(acc, b1, wcol, ln15);
    __syncthreads();
    mac<4>(sA, sB, wrow, wcol, ln15, quad, acc);
    __syncthreads();
    acc_to_sA(acc, sA, wrow, wcol, ln15, quad);
    stageW128(W2t, tid, sB);
    set_bias(acc, b2, wcol, ln15);
    __syncthreads();
    mac<4>(sA, sB, wrow, wcol, ln15, quad, acc);

    float csum[4] = {0.f, 0.f, 0.f, 0.f};
#pragma unroll
    for (int mi = 0; mi < 2; mi++)
#pragma unroll
        for (int r = 0; r < 4; r++) {
            int row = row0 + wrow + mi * 16 + quad * 4 + r;
            if (row < n) {
#pragma unroll
                for (int ni = 0; ni < 4; ni++) {
                    float v = acc[mi][ni][r];
                    int col = wcol + ni * 16 + ln15;
                    h[(size_t)row * HID + col] = v;
                    hb[(size_t)row * HID + col] = f2b(v);
                    csum[ni] += v;
                }
            }
        }
    __syncthreads();
    float* s_cs = (float*)sA;
    if (tid < HID) s_cs[tid] = 0.f;
    __syncthreads();
#pragma unroll
    for (int ni = 0; ni < 4; ni++) {
        float p = csum[ni];
        p += __shfl_xor(p, 16);
        p += __shfl_xor(p, 32);
        if (quad == 0) atomicAdd(&s_cs[wcol + ni * 16 + ln15], p);
    }
    __syncthreads();
    if (tid < HID) atomicAdd(&gsum0[tid], s_cs[tid]);
}

// ---------------- fused node update ----------------
// FINAL=false: write hb only (fp32 h in d_out keeps init values; deg==0 nodes never update),
//              colsum for next iter (updated rows: fp32 v; stale rows: read fp32 h = init vals).
// FINAL=true:  write fp32 h for updated rows only; no hb, no colsum.

template <bool FINAL>
__global__ __launch_bounds__(256, 3) void node_fused_k(const u16* __restrict__ msgb, const u16* __restrict__ hbin,
                                                       const u16* __restrict__ W0a, const u16* __restrict__ W0b,
                                                       const u16* __restrict__ W1t, const u16* __restrict__ W2t,
                                                       const float* __restrict__ b0, const float* __restrict__ Wg,
                                                       const float* __restrict__ gsumIn,
                                                       const float* __restrict__ b1, const float* __restrict__ b2,
                                                       const int* __restrict__ deg,
                                                       float* __restrict__ h, u16* __restrict__ hb,
                                                       float* __restrict__ gsumOut, int n) {
    __shared__ u16 sA[64 * LDST];
    __shared__ u16 sB[128 * LDST];
    __shared__ float s_gr[HID];
    __shared__ float s_grW[HID];
    __shared__ float s_red[2];
    int tid = threadIdx.x;
    int lane = tid & 63, wave = tid >> 6;
    int ln15 = lane & 15, quad = lane >> 4;
    int wrow = (wave >> 1) * 32, wcol = (wave & 1) * 64;
    int row0 = blockIdx.x * 64;
    f32x4 acc[2][4];

    stageA128(msgb, row0, tid, sA);
    stageW128(W0a, tid, sB);
    if (tid < HID) {
        float g = gsumIn[tid];
        float s = g * g;
#pragma unroll
        for (int off = 1; off < 64; off <<= 1) s += __shfl_xor(s, off);
        if ((tid & 63) == 0) s_red[tid >> 6] = s;
    }
    __syncthreads();
    if (tid < HID) {
        float inv = 1.f / (sqrtf(s_red[0] + s_red[1]) + 1e-8f);
        s_gr[tid] = gsumIn[tid] * inv;
    }
    __syncthreads();
    if (tid < HID) {
        float a = b0[tid];
#pragma unroll 4
        for (int k = 0; k < HID; k++) a += s_gr[k] * Wg[k * HID + tid];
        s_grW[tid] = a;
    }
    __syncthreads();
    set_bias(acc, s_grW, wcol, ln15);
    mac<4>(sA, sB, wrow, wcol, ln15, quad, acc);     // msg @ W0a
    __syncthreads();
    stageA128(hbin, row0, tid, sA);
    stageW128(W0b, tid, sB);
    __syncthreads();
    mac<4>(sA, sB, wrow, wcol, ln15, quad, acc);     // + h @ W0b
    __syncthreads();
    acc_to_sA(acc, sA, wrow, wcol, ln15, quad);
    stageW128(W1t, tid, sB);
    set_bias(acc, b1, wcol, ln15);
    __syncthreads();
    mac<4>(sA, sB, wrow, wcol, ln15, quad, acc);
    __syncthreads();
    acc_to_sA(acc, sA, wrow, wcol, ln15, quad);
    stageW128(W2t, tid, sB);
    set_bias(acc, b2, wcol, ln15);
    __syncthreads();
    mac<4>(sA, sB, wrow, wcol, ln15, quad, acc);

    __syncthreads();
    float* s_rs = (float*)sA;             // [64] row sum-of-squares
    float* s_cs = (float*)sA + 64;        // [128] col sums
    if (tid < 64) s_rs[tid] = 0.f;
    else if (tid < 192) s_cs[tid - 64] = 0.f;
    __syncthreads();
#pragma unroll
    for (int mi = 0; mi < 2; mi++)
#pragma unroll
        for (int r = 0; r < 4; r++) {
            float p = 0.f;
#pragma unroll
            for (int ni = 0; ni < 4; ni++) { float v = acc[mi][ni][r]; p += v * v; }
            p += __shfl_xor(p, 1); p += __shfl_xor(p, 2);
            p += __shfl_xor(p, 4); p += __shfl_xor(p, 8);
            if (ln15 == 0) atomicAdd(&s_rs[wrow + mi * 16 + quad * 4 + r], p);
        }
    __syncthreads();
    float csum[4] = {0.f, 0.f, 0.f, 0.f};
#pragma unroll
    for (int mi = 0; mi < 2; mi++)
#pragma unroll
        for (int r = 0; r < 4; r++) {
            int rl = wrow + mi * 16 + quad * 4 + r;
            int row = row0 + rl;
            if (row < n) {
                bool upd = deg[row] > 0;
                float inv = 1.f / (sqrtf(s_rs[rl]) + 1e-8f);
#pragma unroll
                for (int ni = 0; ni < 4; ni++) {
                    int col = wcol + ni * 16 + ln15;
                    if (FINAL) {
                        if (upd) h[(size_t)row * HID + col] = acc[mi][ni][r] * inv;
                    } else {
                        float v;
                        if (upd) {
                            v = acc[mi][ni][r] * inv;
                            hb[(size_t)row * HID + col] = f2b(v);
                        } else {
                            v = h[(size_t)row * HID + col];  // init value (deg==0 never updates)
                        }
                        csum[ni] += v;
                    }
                }
            }
        }
    if (!FINAL) {
#pragma unroll
        for (int ni = 0; ni < 4; ni++) {
            float p = csum[ni];
            p += __shfl_xor(p, 16);
            p += __shfl_xor(p, 32);
            if (quad == 0) atomicAdd(&s_cs[wcol + ni * 16 + ln15], p);
        }
        __syncthreads();
        if (tid < HID) atomicAdd(&gsumOut[tid], s_cs[tid]);
    }
}

// ---------------- launch ----------------

static inline char* align_up(char* p, size_t a) {
    return (char*)(((uintptr_t)p + a - 1) & ~(uintptr_t)(a - 1));
}

extern "C" void kernel_launch(void* const* d_in, const int* in_sizes, int n_in,
                              void* d_out, int out_size, void* d_ws, size_t ws_size,
                              hipStream_t stream) {
    const float* feat = (const float*)d_in[0];
    const int* src = (const int*)d_in[1];
    const int* dst = (const int*)d_in[2];
    const float* iW0 = (const float*)d_in[3];
    const float* ib0 = (const float*)d_in[4];
    const float* iW1 = (const float*)d_in[5];
    const float* ib1 = (const float*)d_in[6];
    const float* iW2 = (const float*)d_in[7];
    const float* ib2 = (const float*)d_in[8];
    const float* nW0 = (const float*)d_in[9];
    const float* nb0 = (const float*)d_in[10];
    const float* nW1 = (const float*)d_in[11];
    const float* nb1 = (const float*)d_in[12];
    const float* nW2 = (const float*)d_in[13];
    const float* nb2 = (const float*)d_in[14];

    int N = in_sizes[0] / IN_DIM;
    int E = in_sizes[1];
    int n_iter = in_sizes[10] / HID;
    int NB = (N + (1 << NBSH) - 1) >> NBSH;   // 782 for N=50000 (<=1024 assumed)
    float* h = (float*)d_out;

    char* w = (char*)d_ws;
    size_t big2 = (size_t)(N + 64) * HID * sizeof(u16);
    u16* hb   = (u16*)w; w += big2;
    u16* msgb = (u16*)w; w += big2;
    float* gsums = (float*)w; w += (size_t)(n_iter + 1) * HID * sizeof(float);
    u16* Wt = (u16*)w; w += (size_t)(2048 + 2 * 16384 + n_iter * 4 * 16384) * sizeof(u16);
    w = align_up(w, 16);
    int* deg = (int*)w; w += (size_t)N * 4;  w = align_up(w, 16);
    int* row_ptr = (int*)w; w += (size_t)(N + 1) * 4;  w = align_up(w, 16);
    int* bktcnt = (int*)w; w += (size_t)NB * 4;  w = align_up(w, 16);
    int* bktbase = (int*)w; w += (size_t)(NB + 1) * 4;  w = align_up(w, 64);
    int* bcnt = (int*)w; w += (size_t)NB * BPAD * 4;  w = align_up(w, 16);
    int* srcs = (int*)w; w += (size_t)E * 4;  w = align_up(w, 16);
    unsigned* ebuf = (unsigned*)w; w += (size_t)E * 4;
    (void)ws_size; (void)n_in; (void)out_size;

    // Wt layout offsets (bf16 elems)
    const int OFF_IW0 = 0;
    const int OFF_IW1 = 2048;
    const int OFF_IW2 = 2048 + 16384;
    const int OFF_IT = 2048 + 2 * 16384;  // per iter: W0a, W0b, W1, W2 (4 x 16384)

    WJobs jobs;
    int nj = 0;
    jobs.src[nj] = iW0; jobs.dstoff[nj] = OFF_IW0; jobs.ks[nj] = 4; nj++;
    jobs.src[nj] = iW1; jobs.dstoff[nj] = OFF_IW1; jobs.ks[nj] = 7; nj++;
    jobs.src[nj] = iW2; jobs.dstoff[nj] = OFF_IW2; jobs.ks[nj] = 7; nj++;
    for (int i = 0; i < n_iter && nj + 4 <= 16; i++) {
        int base = OFF_IT + i * 4 * 16384;
        jobs.src[nj] = nW0 + (size_t)i * 3 * HID * HID;               jobs.dstoff[nj] = base;             jobs.ks[nj] = 7; nj++;
        jobs.src[nj] = nW0 + (size_t)i * 3 * HID * HID + HID * HID;   jobs.dstoff[nj] = base + 16384;     jobs.ks[nj] = 7; nj++;
        jobs.src[nj] = nW1 + (size_t)i * HID * HID;                   jobs.dstoff[nj] = base + 2 * 16384; jobs.ks[nj] = 7; nj++;
        jobs.src[nj] = nW2 + (size_t)i * HID * HID;                   jobs.dstoff[nj] = base + 3 * 16384; jobs.ks[nj] = 7; nj++;
    }

    hipMemsetAsync(bktcnt, 0, (size_t)NB * 4, stream);
    hipMemsetAsync(gsums, 0, (size_t)(n_iter + 1) * HID * sizeof(float), stream);

    wprep_k<<<nj, 256, 0, stream>>>(jobs, Wt);

    int cg = (E + CH - 1) / CH;
    hist_k<<<cg, 256, 0, stream>>>(dst, bktcnt, E, NB);
    bscan_k<<<1, 1024, 0, stream>>>(bktcnt, bktbase, bcnt, row_ptr, NB, N, E);
    bin_k<<<cg, 256, 0, stream>>>(src, dst, bcnt, ebuf, E, NB);
    fill2_k<<<NB, 256, 0, stream>>>(ebuf, bktbase, row_ptr, deg, srcs, N);

    int gb = (N + 63) / 64;
    int rb = (N + 3) / 4;
    init_fused_k<<<gb, 256, 0, stream>>>(feat, Wt + OFF_IW0, Wt + OFF_IW1, Wt + OFF_IW2,
                                         ib0, ib1, ib2, h, hb, gsums, N);

    for (int i = 0; i < n_iter; i++) {
        const u16* Wit = Wt + OFF_IT + (size_t)i * 4 * 16384;
        const float* Wg = nW0 + (size_t)i * 3 * HID * HID + 2 * HID * HID;
        msg_k<<<rb, 256, 0, stream>>>(hb, row_ptr, srcs, msgb, N);
        if (i + 1 < n_iter) {
            node_fused_k<false><<<gb, 256, 0, stream>>>(msgb, hb, Wit, Wit + 16384, Wit + 2 * 16384,
                                                        Wit + 3 * 16384, nb0 + (size_t)i * HID, Wg,
                                                        gsums + (size_t)i * HID, nb1 + (size_t)i * HID,
                                                        nb2 + (size_t)i * HID, deg, h, hb,
                                                        gsums + (size_t)(i + 1) * HID, N);
        } else {
            node_fused_k<true><<<gb, 256, 0, stream>>>(msgb, hb, Wit, Wit + 16384, Wit + 2 * 16384,
                                                       Wit + 3 * 16384, nb0 + (size_t)i * HID, Wg,
                                                       gsums + (size_t)i * HID, nb1 + (size_t)i * HID,
                                                       nb2 + (size_t)i * HID, deg, h, hb,
                                                       nullptr, N);
        }
    }
}

// Round 11
// 491.351 us; speedup vs baseline: 9.1015x; 1.0829x over previous
//
#include <hip/hip_runtime.h>
#include <hip/hip_bf16.h>

#define HID 128
#define IN_DIM 16
#define LDST 136   // LDS row stride in bf16 elems (272 B)
#define NBSH 6     // bucket = dst >> 6  (64 dsts/bucket)
#define BPAD 16    // bucket counter padding (ints) -> one 64B line per counter
#define SRCM 0x3ffffffu
#define CH 8192    // edges per chunk (hist_k / bin_k)
#define NBMAX 1024

typedef unsigned short u16;
typedef __attribute__((ext_vector_type(8))) short short8;
typedef __attribute__((ext_vector_type(4))) float f32x4;

__device__ __forceinline__ u16 f2b(float f) {  // RNE
    unsigned u = __float_as_uint(f);
    return (u16)((u + 0x7FFF + ((u >> 16) & 1)) >> 16);
}

// ---------------- graph prep ----------------
// Lesson (r9): E-scale scattered global atomics write through at ~32B/atomic. LDS only.

__global__ __launch_bounds__(256) void hist_k(const int* __restrict__ dst, int* __restrict__ bktcnt,
                                              int E, int nb) {
    __shared__ int hist[NBMAX];
    int tid = threadIdx.x;
    int base = blockIdx.x * CH;
    int cnt = E - base; if (cnt > CH) cnt = CH;
    for (int i = tid; i < nb; i += 256) hist[i] = 0;
    __syncthreads();
    for (int j = tid; j < cnt; j += 256) atomicAdd(&hist[dst[base + j] >> NBSH], 1);
    __syncthreads();
    for (int i = tid; i < nb; i += 256) {
        int c = hist[i];
        if (c > 0) atomicAdd(&bktcnt[i], c);
    }
}

__global__ __launch_bounds__(1024) void bscan_k(const int* __restrict__ bktcnt, int* __restrict__ bktbase,
                                                int* __restrict__ bcnt, int* __restrict__ row_ptr,
                                                int nb, int n, int E) {
    __shared__ int sbuf[1024];
    int t = threadIdx.x;
    int v = (t < nb) ? bktcnt[t] : 0;
    sbuf[t] = v;
    __syncthreads();
    for (int off = 1; off < 1024; off <<= 1) {
        int a = (t >= off) ? sbuf[t - off] : 0;
        __syncthreads();
        sbuf[t] += a;
        __syncthreads();
    }
    if (t < nb) {
        int excl = sbuf[t] - v;
        bktbase[t] = excl;
        bcnt[t * BPAD] = excl;
    }
    if (t == 0) { bktbase[nb] = E; row_ptr[n] = E; }
}

__global__ __launch_bounds__(256) void bin_k(const int* __restrict__ src, const int* __restrict__ dst,
                                             int* __restrict__ bcnt, unsigned* __restrict__ ebuf,
                                             int E, int nb) {
    __shared__ unsigned stage[CH];
    __shared__ u16 sbk[CH];
    __shared__ int hist[NBMAX];
    __shared__ int lofs[NBMAX];
    __shared__ int sbase[NBMAX];
    __shared__ int scan256[256];
    int tid = threadIdx.x;
    int base = blockIdx.x * CH;
    int cnt = E - base; if (cnt > CH) cnt = CH;

    for (int i = tid; i < nb; i += 256) hist[i] = 0;
    __syncthreads();
    for (int j = tid; j < cnt; j += 256) {
        int d = dst[base + j];
        atomicAdd(&hist[d >> NBSH], 1);
    }
    __syncthreads();
    int psum[4];
    int ts = 0;
#pragma unroll
    for (int q = 0; q < 4; q++) {
        int idx = tid * 4 + q;
        int hv = (idx < nb) ? hist[idx] : 0;
        psum[q] = ts;
        ts += hv;
    }
    scan256[tid] = ts;
    __syncthreads();
    for (int off = 1; off < 256; off <<= 1) {
        int a = (tid >= off) ? scan256[tid - off] : 0;
        __syncthreads();
        scan256[tid] += a;
        __syncthreads();
    }
    int tbase = (tid > 0) ? scan256[tid - 1] : 0;
#pragma unroll
    for (int q = 0; q < 4; q++) {
        int idx = tid * 4 + q;
        if (idx < nb) lofs[idx] = tbase + psum[q];
    }
    __syncthreads();
    for (int i = tid; i < nb; i += 256) {
        int c = hist[i];
        if (c > 0) {
            int g = atomicAdd(&bcnt[i * BPAD], c);
            sbase[i] = g - lofs[i];
        }
    }
    __syncthreads();
    for (int j = tid; j < cnt; j += 256) {
        int e = base + j;
        int d = dst[e];
        int b = d >> NBSH;
        int r = atomicAdd(&lofs[b], 1);
        stage[r] = (unsigned)src[e] | ((unsigned)(d & 63) << 26);
        sbk[r] = (u16)b;
    }
    __syncthreads();
    for (int s = tid; s < cnt; s += 256) {
        int b = sbk[s];
        ebuf[sbase[b] + s] = stage[s];
    }
}

__global__ __launch_bounds__(256) void fill2_k(const unsigned* __restrict__ ebuf, const int* __restrict__ bktbase,
                                               int* __restrict__ row_ptr, int* __restrict__ deg,
                                               int* __restrict__ srcs, int n) {
    __shared__ int hist64[64];
    __shared__ int lofs[64];
    int tid = threadIdx.x;
    int b = blockIdx.x;
    int e0 = bktbase[b], e1 = bktbase[b + 1];
    if (tid < 64) hist64[tid] = 0;
    __syncthreads();
    for (int i = e0 + tid; i < e1; i += 256) atomicAdd(&hist64[ebuf[i] >> 26], 1);
    __syncthreads();
    if (tid < 64) {
        int d = hist64[tid];
        int s = d;
#pragma unroll
        for (int off = 1; off < 64; off <<= 1) {
            int t = __shfl_up(s, off);
            if (tid >= off) s += t;
        }
        int excl = e0 + s - d;
        int gi = (b << NBSH) + tid;
        if (gi < n) { row_ptr[gi] = excl; deg[gi] = d; }
        lofs[tid] = excl;
    }
    __syncthreads();
    for (int i = e0 + tid; i < e1; i += 256) {
        unsigned p = ebuf[i];
        int d = (int)(p >> 26);
        int pos = atomicAdd(&lofs[d], 1);
        srcs[pos] = (int)(p & SRCM);
    }
}

// ---------------- weight prep: fp32 [K,128] -> bf16 [128][K] (n-major) ----------------

struct WJobs {
    const float* src[16];
    int dstoff[16];
    int ks[16];
};

__global__ __launch_bounds__(256) void wprep_k(WJobs j, u16* __restrict__ Wt) {
    int m = blockIdx.x;
    const float* s = j.src[m];
    u16* d = Wt + j.dstoff[m];
    int ks = j.ks[m];
    int K = 1 << ks;
    int tot = K * HID;
    for (int idx = threadIdx.x; idx < tot; idx += 256) {
        int nn = idx >> ks;
        int kk = idx & (K - 1);
        d[idx] = f2b(s[kk * HID + nn]);
    }
}

// ---------------- message aggregation (wave/dst) + grW side-job in last block ----------------

__global__ __launch_bounds__(256) void msg_k(const u16* __restrict__ hb, const int* __restrict__ row_ptr,
                                             const int* __restrict__ srcs, u16* __restrict__ msgb, int n,
                                             const float* __restrict__ gsumIn, const float* __restrict__ Wg,
                                             const float* __restrict__ b0, float* __restrict__ grW) {
    if (blockIdx.x == gridDim.x - 1) {
        // dedicated block: grW = b0 + rownorm(gsum) @ Wg (overlapped with gather blocks)
        __shared__ float sred[2];
        __shared__ float sgr[HID];
        int t = threadIdx.x;
        if (t < HID) {
            float g = gsumIn[t];
            float s = g * g;
#pragma unroll
            for (int off = 1; off < 64; off <<= 1) s += __shfl_xor(s, off);
            if ((t & 63) == 0) sred[t >> 6] = s;
        }
        __syncthreads();
        if (t < HID) {
            float inv = 1.f / (sqrtf(sred[0] + sred[1]) + 1e-8f);
            sgr[t] = gsumIn[t] * inv;
        }
        __syncthreads();
        if (t < HID) {
            float a = b0[t];
#pragma unroll 4
            for (int k = 0; k < HID; k++) a += sgr[k] * Wg[k * HID + t];
            grW[t] = a;
        }
        return;
    }
    int wave = threadIdx.x >> 6, lane = threadIdx.x & 63;
    int d = blockIdx.x * 4 + wave;
    if (d >= n) return;
    int e = row_ptr[d], e1 = row_ptr[d + 1];
    float a0 = 0.f, a1 = 0.f;
    for (; e + 3 < e1; e += 4) {
        int s0 = srcs[e], s1 = srcs[e + 1], s2 = srcs[e + 2], s3 = srcs[e + 3];
        unsigned v0 = *(const unsigned*)(hb + (size_t)s0 * HID + lane * 2);
        unsigned v1 = *(const unsigned*)(hb + (size_t)s1 * HID + lane * 2);
        unsigned v2 = *(const unsigned*)(hb + (size_t)s2 * HID + lane * 2);
        unsigned v3 = *(const unsigned*)(hb + (size_t)s3 * HID + lane * 2);
        a0 += __uint_as_float(v0 << 16) + __uint_as_float(v1 << 16) +
              __uint_as_float(v2 << 16) + __uint_as_float(v3 << 16);
        a1 += __uint_as_float(v0 & 0xffff0000u) + __uint_as_float(v1 & 0xffff0000u) +
              __uint_as_float(v2 & 0xffff0000u) + __uint_as_float(v3 & 0xffff0000u);
    }
    for (; e < e1; e++) {
        unsigned v = *(const unsigned*)(hb + (size_t)srcs[e] * HID + lane * 2);
        a0 += __uint_as_float(v << 16);
        a1 += __uint_as_float(v & 0xffff0000u);
    }
    unsigned out = (unsigned)f2b(a0) | ((unsigned)f2b(a1) << 16);
    *(unsigned*)(msgb + (size_t)d * HID + lane * 2) = out;
}

// ---------------- MFMA building blocks: 128x128 C-tile, 8 waves (4x2), 512 threads ----------------

// load/write a 128x128 u16 tile (rows contiguous at stride HID in global, LDST in LDS)
__device__ __forceinline__ void load_tile(const u16* __restrict__ base, int tid, uint4 p[4]) {
#pragma unroll
    for (int q = 0; q < 4; q++) {
        int c = tid + q * 512;
        p[q] = *(const uint4*)(base + (size_t)(c >> 4) * HID + (c & 15) * 8);
    }
}

__device__ __forceinline__ void write_tile(const uint4 p[4], int tid, u16* s) {
#pragma unroll
    for (int q = 0; q < 4; q++) {
        int c = tid + q * 512;
        *(uint4*)(s + (c >> 4) * LDST + (c & 15) * 8) = p[q];
    }
}

__device__ __forceinline__ void stageFeat(const float* __restrict__ feat, int row0, int n, int tid, u16* sA) {
    int row = tid >> 2, coff = tid & 3;   // 512 threads: 128 rows x 4
    ushort4 o = make_ushort4(0, 0, 0, 0);
    if (row0 + row < n) {
        float4 v = *(const float4*)(feat + (size_t)(row0 + row) * IN_DIM + coff * 4);
        o = make_ushort4(f2b(v.x), f2b(v.y), f2b(v.z), f2b(v.w));
    }
    *(ushort4*)(sA + row * LDST + coff * 4) = o;
    *(ushort4*)(sA + row * LDST + 16 + coff * 4) = make_ushort4(0, 0, 0, 0);  // zero-pad K 16->32
}

__device__ __forceinline__ void stageW16(const u16* __restrict__ Wt, int tid, u16* sB) {
    if (tid < 256) {
        int row = tid >> 1, h8 = tid & 1;   // 128 rows x 2 halves
        uint4 v = *(const uint4*)(Wt + row * IN_DIM + h8 * 8);
        *(uint4*)(sB + row * LDST + h8 * 8) = v;
        *(uint4*)(sB + row * LDST + 16 + h8 * 8) = make_uint4(0, 0, 0, 0);
    }
}

template <int KSTEPS>
__device__ __forceinline__ void mac(const u16* sA, const u16* sB, int wrow, int wcol,
                                    int ln15, int quad, f32x4 acc[2][4]) {
#pragma unroll
    for (int kk = 0; kk < KSTEPS; kk++) {
        short8 a[2], b[4];
#pragma unroll
        for (int mi = 0; mi < 2; mi++)
            a[mi] = *(const short8*)(sA + (wrow + mi * 16 + ln15) * LDST + kk * 32 + quad * 8);
#pragma unroll
        for (int ni = 0; ni < 4; ni++)
            b[ni] = *(const short8*)(sB + (wcol + ni * 16 + ln15) * LDST + kk * 32 + quad * 8);
#pragma unroll
        for (int mi = 0; mi < 2; mi++)
#pragma unroll
            for (int ni = 0; ni < 4; ni++)
                acc[mi][ni] = __builtin_amdgcn_mfma_f32_16x16x32_bf16(a[mi], b[ni], acc[mi][ni], 0, 0, 0);
    }
}

__device__ __forceinline__ void set_bias(f32x4 acc[2][4], const float* __restrict__ bias, int wcol, int ln15) {
#pragma unroll
    for (int ni = 0; ni < 4; ni++) {
        float bv = bias[wcol + ni * 16 + ln15];
#pragma unroll
        for (int mi = 0; mi < 2; mi++) acc[mi][ni] = (f32x4){bv, bv, bv, bv};
    }
}

__device__ __forceinline__ void acc_to_sA(const f32x4 acc[2][4], u16* sA, int wrow, int wcol,
                                          int ln15, int quad) {
#pragma unroll
    for (int mi = 0; mi < 2; mi++)
#pragma unroll
        for (int r = 0; r < 4; r++) {
            int row = wrow + mi * 16 + quad * 4 + r;
#pragma unroll
            for (int ni = 0; ni < 4; ni++)
                sA[row * LDST + wcol + ni * 16 + ln15] = f2b(fmaxf(acc[mi][ni][r], 0.f));
        }
}

// ---------------- fused init MLP (M=128): feat -> relu -> relu -> h (+hb) + colsum ----------------

__global__ __launch_bounds__(512, 4) void init_fused_k(const float* __restrict__ feat,
                                                       const u16* __restrict__ W0t, const u16* __restrict__ W1t,
                                                       const u16* __restrict__ W2t,
                                                       const float* __restrict__ b0, const float* __restrict__ b1,
                                                       const float* __restrict__ b2,
                                                       float* __restrict__ h, u16* __restrict__ hb,
                                                       float* __restrict__ gsum0, int n) {
    __shared__ u16 sA[128 * LDST];
    __shared__ u16 sB[128 * LDST];
    int tid = threadIdx.x;
    int lane = tid & 63, wave = tid >> 6;
    int ln15 = lane & 15, quad = lane >> 4;
    int wrow = (wave >> 1) * 32, wcol = (wave & 1) * 64;
    int row0 = blockIdx.x * 128;
    f32x4 acc[2][4];
    uint4 pB[4];

    stageFeat(feat, row0, n, tid, sA);
    stageW16(W0t, tid, sB);
    load_tile(W1t, tid, pB);            // prefetch next layer's weights
    set_bias(acc, b0, wcol, ln15);
    __syncthreads();
    mac<1>(sA, sB, wrow, wcol, ln15, quad, acc);
    __syncthreads();
    acc_to_sA(acc, sA, wrow, wcol, ln15, quad);
    write_tile(pB, tid, sB);            // W1
    load_tile(W2t, tid, pB);            // prefetch W2
    set_bias(acc, b1, wcol, ln15);
    __syncthreads();
    mac<4>(sA, sB, wrow, wcol, ln15, quad, acc);
    __syncthreads();
    acc_to_sA(acc, sA, wrow, wcol, ln15, quad);
    write_tile(pB, tid, sB);            // W2
    set_bias(acc, b2, wcol, ln15);
    __syncthreads();
    mac<4>(sA, sB, wrow, wcol, ln15, quad, acc);

    float csum[4] = {0.f, 0.f, 0.f, 0.f};
#pragma unroll
    for (int mi = 0; mi < 2; mi++)
#pragma unroll
        for (int r = 0; r < 4; r++) {
            int row = row0 + wrow + mi * 16 + quad * 4 + r;
            if (row < n) {
#pragma unroll
                for (int ni = 0; ni < 4; ni++) {
                    float v = acc[mi][ni][r];
                    int col = wcol + ni * 16 + ln15;
                    h[(size_t)row * HID + col] = v;
                    hb[(size_t)row * HID + col] = f2b(v);
                    csum[ni] += v;
                }
            }
        }
    __syncthreads();
    float* s_cs = (float*)sA;
    if (tid < HID) s_cs[tid] = 0.f;
    __syncthreads();
#pragma unroll
    for (int ni = 0; ni < 4; ni++) {
        float p = csum[ni];
        p += __shfl_xor(p, 16);
        p += __shfl_xor(p, 32);
        if (quad == 0) atomicAdd(&s_cs[wcol + ni * 16 + ln15], p);
    }
    __syncthreads();
    if (tid < HID) atomicAdd(&gsum0[tid], s_cs[tid]);
}

// ---------------- fused node update (M=128, register-prefetch pipeline) ----------------

template <bool FINAL>
__global__ __launch_bounds__(512, 4) void node_fused_k(const u16* __restrict__ msgb, const u16* __restrict__ hbin,
                                                       const u16* __restrict__ W0a, const u16* __restrict__ W0b,
                                                       const u16* __restrict__ W1t, const u16* __restrict__ W2t,
                                                       const float* __restrict__ grW,
                                                       const float* __restrict__ b1, const float* __restrict__ b2,
                                                       const int* __restrict__ deg,
                                                       float* __restrict__ h, u16* __restrict__ hb,
                                                       float* __restrict__ gsumOut, int n) {
    __shared__ u16 sA[128 * LDST];
    __shared__ u16 sB[128 * LDST];
    int tid = threadIdx.x;
    int lane = tid & 63, wave = tid >> 6;
    int ln15 = lane & 15, quad = lane >> 4;
    int wrow = (wave >> 1) * 32, wcol = (wave & 1) * 64;
    int row0 = blockIdx.x * 128;
    f32x4 acc[2][4];
    uint4 pA[4], pB[4];

    load_tile(msgb + (size_t)row0 * HID, tid, pA);
    load_tile(W0a, tid, pB);
    write_tile(pA, tid, sA);
    write_tile(pB, tid, sB);
    load_tile(hbin + (size_t)row0 * HID, tid, pA);   // prefetch phase-2 operands
    load_tile(W0b, tid, pB);
    set_bias(acc, grW, wcol, ln15);
    __syncthreads();
    mac<4>(sA, sB, wrow, wcol, ln15, quad, acc);     // msg @ W0a
    __syncthreads();
    write_tile(pA, tid, sA);                         // h tile
    write_tile(pB, tid, sB);                         // W0b
    load_tile(W1t, tid, pB);                         // prefetch W1
    __syncthreads();
    mac<4>(sA, sB, wrow, wcol, ln15, quad, acc);     // + h @ W0b
    __syncthreads();
    acc_to_sA(acc, sA, wrow, wcol, ln15, quad);
    write_tile(pB, tid, sB);                         // W1
    load_tile(W2t, tid, pB);                         // prefetch W2
    set_bias(acc, b1, wcol, ln15);
    __syncthreads();
    mac<4>(sA, sB, wrow, wcol, ln15, quad, acc);     // @ W1
    __syncthreads();
    acc_to_sA(acc, sA, wrow, wcol, ln15, quad);
    write_tile(pB, tid, sB);                         // W2
    set_bias(acc, b2, wcol, ln15);
    __syncthreads();
    mac<4>(sA, sB, wrow, wcol, ln15, quad, acc);     // @ W2

    __syncthreads();
    float* s_rs = (float*)sA;             // [128] row sum-of-squares
    float* s_cs = (float*)sA + 128;       // [128] col sums
    if (tid < 128) s_rs[tid] = 0.f;
    else if (tid < 256) s_cs[tid - 128] = 0.f;
    __syncthreads();
#pragma unroll
    for (int mi = 0; mi < 2; mi++)
#pragma unroll
        for (int r = 0; r < 4; r++) {
            float p = 0.f;
#pragma unroll
            for (int ni = 0; ni < 4; ni++) { float v = acc[mi][ni][r]; p += v * v; }
            p += __shfl_xor(p, 1); p += __shfl_xor(p, 2);
            p += __shfl_xor(p, 4); p += __shfl_xor(p, 8);
            if (ln15 == 0) atomicAdd(&s_rs[wrow + mi * 16 + quad * 4 + r], p);
        }
    __syncthreads();
    float csum[4] = {0.f, 0.f, 0.f, 0.f};
#pragma unroll
    for (int mi = 0; mi < 2; mi++)
#pragma unroll
        for (int r = 0; r < 4; r++) {
            int rl = wrow + mi * 16 + quad * 4 + r;
            int row = row0 + rl;
            if (row < n) {
                bool upd = deg[row] > 0;
                float inv = 1.f / (sqrtf(s_rs[rl]) + 1e-8f);
#pragma unroll
                for (int ni = 0; ni < 4; ni++) {
                    int col = wcol + ni * 16 + ln15;
                    if (FINAL) {
                        if (upd) h[(size_t)row * HID + col] = acc[mi][ni][r] * inv;
                    } else {
                        float v;
                        if (upd) {
                            v = acc[mi][ni][r] * inv;
                            hb[(size_t)row * HID + col] = f2b(v);
                        } else {
                            v = h[(size_t)row * HID + col];  // init value (deg==0 never updates)
                        }
                        csum[ni] += v;
                    }
                }
            }
        }
    if (!FINAL) {
#pragma unroll
        for (int ni = 0; ni < 4; ni++) {
            float p = csum[ni];
            p += __shfl_xor(p, 16);
            p += __shfl_xor(p, 32);
            if (quad == 0) atomicAdd(&s_cs[wcol + ni * 16 + ln15], p);
        }
        __syncthreads();
        if (tid < HID) atomicAdd(&gsumOut[tid], s_cs[tid]);
    }
}

// ---------------- launch ----------------

static inline char* align_up(char* p, size_t a) {
    return (char*)(((uintptr_t)p + a - 1) & ~(uintptr_t)(a - 1));
}

extern "C" void kernel_launch(void* const* d_in, const int* in_sizes, int n_in,
                              void* d_out, int out_size, void* d_ws, size_t ws_size,
                              hipStream_t stream) {
    const float* feat = (const float*)d_in[0];
    const int* src = (const int*)d_in[1];
    const int* dst = (const int*)d_in[2];
    const float* iW0 = (const float*)d_in[3];
    const float* ib0 = (const float*)d_in[4];
    const float* iW1 = (const float*)d_in[5];
    const float* ib1 = (const float*)d_in[6];
    const float* iW2 = (const float*)d_in[7];
    const float* ib2 = (const float*)d_in[8];
    const float* nW0 = (const float*)d_in[9];
    const float* nb0 = (const float*)d_in[10];
    const float* nW1 = (const float*)d_in[11];
    const float* nb1 = (const float*)d_in[12];
    const float* nW2 = (const float*)d_in[13];
    const float* nb2 = (const float*)d_in[14];

    int N = in_sizes[0] / IN_DIM;
    int E = in_sizes[1];
    int n_iter = in_sizes[10] / HID;
    int NB = (N + (1 << NBSH) - 1) >> NBSH;
    float* h = (float*)d_out;

    char* w = (char*)d_ws;
    size_t big2 = (size_t)(N + 128) * HID * sizeof(u16);  // +128 pad for M=128 tiles
    u16* hb   = (u16*)w; w += big2;
    u16* msgb = (u16*)w; w += big2;
    float* gsums = (float*)w; w += (size_t)(n_iter + 1) * HID * sizeof(float);
    float* grW = (float*)w; w += 1024;
    u16* Wt = (u16*)w; w += (size_t)(2048 + 2 * 16384 + n_iter * 4 * 16384) * sizeof(u16);
    w = align_up(w, 16);
    int* deg = (int*)w; w += (size_t)N * 4;  w = align_up(w, 16);
    int* row_ptr = (int*)w; w += (size_t)(N + 1) * 4;  w = align_up(w, 16);
    int* bktcnt = (int*)w; w += (size_t)NB * 4;  w = align_up(w, 16);
    int* bktbase = (int*)w; w += (size_t)(NB + 1) * 4;  w = align_up(w, 64);
    int* bcnt = (int*)w; w += (size_t)NB * BPAD * 4;  w = align_up(w, 16);
    int* srcs = (int*)w; w += (size_t)E * 4;  w = align_up(w, 16);
    unsigned* ebuf = (unsigned*)w; w += (size_t)E * 4;
    (void)ws_size; (void)n_in; (void)out_size;

    const int OFF_IW0 = 0;
    const int OFF_IW1 = 2048;
    const int OFF_IW2 = 2048 + 16384;
    const int OFF_IT = 2048 + 2 * 16384;

    WJobs jobs;
    int nj = 0;
    jobs.src[nj] = iW0; jobs.dstoff[nj] = OFF_IW0; jobs.ks[nj] = 4; nj++;
    jobs.src[nj] = iW1; jobs.dstoff[nj] = OFF_IW1; jobs.ks[nj] = 7; nj++;
    jobs.src[nj] = iW2; jobs.dstoff[nj] = OFF_IW2; jobs.ks[nj] = 7; nj++;
    for (int i = 0; i < n_iter && nj + 4 <= 16; i++) {
        int base = OFF_IT + i * 4 * 16384;
        jobs.src[nj] = nW0 + (size_t)i * 3 * HID * HID;               jobs.dstoff[nj] = base;             jobs.ks[nj] = 7; nj++;
        jobs.src[nj] = nW0 + (size_t)i * 3 * HID * HID + HID * HID;   jobs.dstoff[nj] = base + 16384;     jobs.ks[nj] = 7; nj++;
        jobs.src[nj] = nW1 + (size_t)i * HID * HID;                   jobs.dstoff[nj] = base + 2 * 16384; jobs.ks[nj] = 7; nj++;
        jobs.src[nj] = nW2 + (size_t)i * HID * HID;                   jobs.dstoff[nj] = base + 3 * 16384; jobs.ks[nj] = 7; nj++;
    }

    hipMemsetAsync(bktcnt, 0, (size_t)NB * 4, stream);
    hipMemsetAsync(gsums, 0, (size_t)(n_iter + 1) * HID * sizeof(float), stream);

    wprep_k<<<nj, 256, 0, stream>>>(jobs, Wt);

    int cg = (E + CH - 1) / CH;
    hist_k<<<cg, 256, 0, stream>>>(dst, bktcnt, E, NB);
    bscan_k<<<1, 1024, 0, stream>>>(bktcnt, bktbase, bcnt, row_ptr, NB, N, E);
    bin_k<<<cg, 256, 0, stream>>>(src, dst, bcnt, ebuf, E, NB);
    fill2_k<<<NB, 256, 0, stream>>>(ebuf, bktbase, row_ptr, deg, srcs, N);

    int gb = (N + 127) / 128;
    int rb = (N + 3) / 4;
    init_fused_k<<<gb, 512, 0, stream>>>(feat, Wt + OFF_IW0, Wt + OFF_IW1, Wt + OFF_IW2,
                                         ib0, ib1, ib2, h, hb, gsums, N);

    for (int i = 0; i < n_iter; i++) {
        const u16* Wit = Wt + OFF_IT + (size_t)i * 4 * 16384;
        const float* Wg = nW0 + (size_t)i * 3 * HID * HID + 2 * HID * HID;
        msg_k<<<rb + 1, 256, 0, stream>>>(hb, row_ptr, srcs, msgb, N,
                                          gsums + (size_t)i * HID, Wg, nb0 + (size_t)i * HID, grW);
        if (i + 1 < n_iter) {
            node_fused_k<false><<<gb, 512, 0, stream>>>(msgb, hb, Wit, Wit + 16384, Wit + 2 * 16384,
                                                        Wit + 3 * 16384, grW, nb1 + (size_t)i * HID,
                                                        nb2 + (size_t)i * HID, deg, h, hb,
                                                        gsums + (size_t)(i + 1) * HID, N);
        } else {
            node_fused_k<true><<<gb, 512, 0, stream>>>(msgb, hb, Wit, Wit + 16384, Wit + 2 * 16384,
                                                       Wit + 3 * 16384, grW, nb1 + (size_t)i * HID,
                                                       nb2 + (size_t)i * HID, deg, h, hb,
                                                       nullptr, N);
        }
    }
}

// Round 12
// 485.260 us; speedup vs baseline: 9.2158x; 1.0126x over previous
//
#include <hip/hip_runtime.h>
#include <hip/hip_bf16.h>

#define HID 128
#define IN_DIM 16
#define LDST 136   // LDS row stride in bf16 elems (272 B)
#define NBSH 6     // bucket = dst >> 6  (64 dsts/bucket)
#define BPAD 16    // bucket counter padding (ints) -> one 64B line per counter
#define SRCM 0x3ffffffu
#define CH 8192    // edges per chunk (hist_k / bin_k)
#define NBMAX 1024

typedef unsigned short u16;
typedef __attribute__((ext_vector_type(8))) short short8;
typedef __attribute__((ext_vector_type(4))) float f32x4;

__device__ __forceinline__ u16 f2b(float f) {  // RNE
    unsigned u = __float_as_uint(f);
    return (u16)((u + 0x7FFF + ((u >> 16) & 1)) >> 16);
}

// ---------------- graph prep ----------------
// Lesson (r9): E-scale scattered global atomics write through at ~32B/atomic. LDS only.

__global__ __launch_bounds__(256) void hist_k(const int* __restrict__ dst, int* __restrict__ bktcnt,
                                              int E, int nb) {
    __shared__ int hist[NBMAX];
    int tid = threadIdx.x;
    int base = blockIdx.x * CH;
    int cnt = E - base; if (cnt > CH) cnt = CH;
    for (int i = tid; i < nb; i += 256) hist[i] = 0;
    __syncthreads();
    for (int j = tid; j < cnt; j += 256) atomicAdd(&hist[dst[base + j] >> NBSH], 1);
    __syncthreads();
    for (int i = tid; i < nb; i += 256) {
        int c = hist[i];
        if (c > 0) atomicAdd(&bktcnt[i], c);
    }
}

__global__ __launch_bounds__(1024) void bscan_k(const int* __restrict__ bktcnt, int* __restrict__ bktbase,
                                                int* __restrict__ bcnt, int* __restrict__ row_ptr,
                                                int nb, int n, int E) {
    __shared__ int sbuf[1024];
    int t = threadIdx.x;
    int v = (t < nb) ? bktcnt[t] : 0;
    sbuf[t] = v;
    __syncthreads();
    for (int off = 1; off < 1024; off <<= 1) {
        int a = (t >= off) ? sbuf[t - off] : 0;
        __syncthreads();
        sbuf[t] += a;
        __syncthreads();
    }
    if (t < nb) {
        int excl = sbuf[t] - v;
        bktbase[t] = excl;
        bcnt[t * BPAD] = excl;
    }
    if (t == 0) { bktbase[nb] = E; row_ptr[n] = E; }
}

__global__ __launch_bounds__(256) void bin_k(const int* __restrict__ src, const int* __restrict__ dst,
                                             int* __restrict__ bcnt, unsigned* __restrict__ ebuf,
                                             int E, int nb) {
    __shared__ unsigned stage[CH];
    __shared__ u16 sbk[CH];
    __shared__ int hist[NBMAX];
    __shared__ int lofs[NBMAX];
    __shared__ int sbase[NBMAX];
    __shared__ int scan256[256];
    int tid = threadIdx.x;
    int base = blockIdx.x * CH;
    int cnt = E - base; if (cnt > CH) cnt = CH;

    for (int i = tid; i < nb; i += 256) hist[i] = 0;
    __syncthreads();
    for (int j = tid; j < cnt; j += 256) {
        int d = dst[base + j];
        atomicAdd(&hist[d >> NBSH], 1);
    }
    __syncthreads();
    int psum[4];
    int ts = 0;
#pragma unroll
    for (int q = 0; q < 4; q++) {
        int idx = tid * 4 + q;
        int hv = (idx < nb) ? hist[idx] : 0;
        psum[q] = ts;
        ts += hv;
    }
    scan256[tid] = ts;
    __syncthreads();
    for (int off = 1; off < 256; off <<= 1) {
        int a = (tid >= off) ? scan256[tid - off] : 0;
        __syncthreads();
        scan256[tid] += a;
        __syncthreads();
    }
    int tbase = (tid > 0) ? scan256[tid - 1] : 0;
#pragma unroll
    for (int q = 0; q < 4; q++) {
        int idx = tid * 4 + q;
        if (idx < nb) lofs[idx] = tbase + psum[q];
    }
    __syncthreads();
    for (int i = tid; i < nb; i += 256) {
        int c = hist[i];
        if (c > 0) {
            int g = atomicAdd(&bcnt[i * BPAD], c);
            sbase[i] = g - lofs[i];
        }
    }
    __syncthreads();
    for (int j = tid; j < cnt; j += 256) {
        int e = base + j;
        int d = dst[e];
        int b = d >> NBSH;
        int r = atomicAdd(&lofs[b], 1);
        stage[r] = (unsigned)src[e] | ((unsigned)(d & 63) << 26);
        sbk[r] = (u16)b;
    }
    __syncthreads();
    for (int s = tid; s < cnt; s += 256) {
        int b = sbk[s];
        ebuf[sbase[b] + s] = stage[s];
    }
}

__global__ __launch_bounds__(256) void fill2_k(const unsigned* __restrict__ ebuf, const int* __restrict__ bktbase,
                                               int* __restrict__ row_ptr, int* __restrict__ deg,
                                               int* __restrict__ srcs, int n) {
    __shared__ int hist64[64];
    __shared__ int lofs[64];
    int tid = threadIdx.x;
    int b = blockIdx.x;
    int e0 = bktbase[b], e1 = bktbase[b + 1];
    if (tid < 64) hist64[tid] = 0;
    __syncthreads();
    for (int i = e0 + tid; i < e1; i += 256) atomicAdd(&hist64[ebuf[i] >> 26], 1);
    __syncthreads();
    if (tid < 64) {
        int d = hist64[tid];
        int s = d;
#pragma unroll
        for (int off = 1; off < 64; off <<= 1) {
            int t = __shfl_up(s, off);
            if (tid >= off) s += t;
        }
        int excl = e0 + s - d;
        int gi = (b << NBSH) + tid;
        if (gi < n) { row_ptr[gi] = excl; deg[gi] = d; }
        lofs[tid] = excl;
    }
    __syncthreads();
    for (int i = e0 + tid; i < e1; i += 256) {
        unsigned p = ebuf[i];
        int d = (int)(p >> 26);
        int pos = atomicAdd(&lofs[d], 1);
        srcs[pos] = (int)(p & SRCM);
    }
}

// ---------------- weight prep: fp32 [K,128] -> bf16 [128][K] (n-major) ----------------

struct WJobs {
    const float* src[16];
    int dstoff[16];
    int ks[16];
};

__global__ __launch_bounds__(256) void wprep_k(WJobs j, u16* __restrict__ Wt) {
    int m = blockIdx.x;
    const float* s = j.src[m];
    u16* d = Wt + j.dstoff[m];
    int ks = j.ks[m];
    int K = 1 << ks;
    int tot = K * HID;
    for (int idx = threadIdx.x; idx < tot; idx += 256) {
        int nn = idx >> ks;
        int kk = idx & (K - 1);
        d[idx] = f2b(s[kk * HID + nn]);
    }
}

// ---------------- message aggregation: quarter-wave gather (16B/lane), wave per dst ----------------
// 16 lanes cover one 256B hb row -> 4 edges per load instruction; grW side-job in last block.

__global__ __launch_bounds__(256) void msg_k(const u16* __restrict__ hb, const int* __restrict__ row_ptr,
                                             const int* __restrict__ srcs, u16* __restrict__ msgb, int n,
                                             const float* __restrict__ gsumIn, const float* __restrict__ Wg,
                                             const float* __restrict__ b0, float* __restrict__ grW) {
    if (blockIdx.x == gridDim.x - 1) {
        // dedicated block: grW = b0 + rownorm(gsum) @ Wg (overlapped with gather blocks)
        __shared__ float sred[2];
        __shared__ float sgr[HID];
        int t = threadIdx.x;
        if (t < HID) {
            float g = gsumIn[t];
            float s = g * g;
#pragma unroll
            for (int off = 1; off < 64; off <<= 1) s += __shfl_xor(s, off);
            if ((t & 63) == 0) sred[t >> 6] = s;
        }
        __syncthreads();
        if (t < HID) {
            float inv = 1.f / (sqrtf(sred[0] + sred[1]) + 1e-8f);
            sgr[t] = gsumIn[t] * inv;
        }
        __syncthreads();
        if (t < HID) {
            float a = b0[t];
#pragma unroll 4
            for (int k = 0; k < HID; k++) a += sgr[k] * Wg[k * HID + t];
            grW[t] = a;
        }
        return;
    }
    int wave = threadIdx.x >> 6, lane = threadIdx.x & 63;
    int d = blockIdx.x * 4 + wave;
    if (d >= n) return;
    int e = row_ptr[d], e1 = row_ptr[d + 1];
    int g = lane >> 4;       // edge group 0..3
    int l16 = lane & 15;     // 16B chunk within row
    float a[8] = {0.f, 0.f, 0.f, 0.f, 0.f, 0.f, 0.f, 0.f};
    for (; e + 3 < e1; e += 4) {
        int s = srcs[e + g];
        uint4 v = *(const uint4*)(hb + (size_t)s * HID + l16 * 8);
        a[0] += __uint_as_float(v.x << 16);
        a[1] += __uint_as_float(v.x & 0xffff0000u);
        a[2] += __uint_as_float(v.y << 16);
        a[3] += __uint_as_float(v.y & 0xffff0000u);
        a[4] += __uint_as_float(v.z << 16);
        a[5] += __uint_as_float(v.z & 0xffff0000u);
        a[6] += __uint_as_float(v.w << 16);
        a[7] += __uint_as_float(v.w & 0xffff0000u);
    }
    if (e + g < e1) {  // remainder 0..3 edges, group-predicated
        int s = srcs[e + g];
        uint4 v = *(const uint4*)(hb + (size_t)s * HID + l16 * 8);
        a[0] += __uint_as_float(v.x << 16);
        a[1] += __uint_as_float(v.x & 0xffff0000u);
        a[2] += __uint_as_float(v.y << 16);
        a[3] += __uint_as_float(v.y & 0xffff0000u);
        a[4] += __uint_as_float(v.z << 16);
        a[5] += __uint_as_float(v.z & 0xffff0000u);
        a[6] += __uint_as_float(v.w << 16);
        a[7] += __uint_as_float(v.w & 0xffff0000u);
    }
#pragma unroll
    for (int i = 0; i < 8; i++) {
        a[i] += __shfl_xor(a[i], 16);
        a[i] += __shfl_xor(a[i], 32);
    }
    if (g == 0) {
        uint4 o;
        o.x = (unsigned)f2b(a[0]) | ((unsigned)f2b(a[1]) << 16);
        o.y = (unsigned)f2b(a[2]) | ((unsigned)f2b(a[3]) << 16);
        o.z = (unsigned)f2b(a[4]) | ((unsigned)f2b(a[5]) << 16);
        o.w = (unsigned)f2b(a[6]) | ((unsigned)f2b(a[7]) << 16);
        *(uint4*)(msgb + (size_t)d * HID + l16 * 8) = o;
    }
}

// ---------------- MFMA building blocks: 128x128 C-tile, 8 waves (4x2), 512 threads ----------------

__device__ __forceinline__ void load_tile(const u16* __restrict__ base, int tid, uint4 p[4]) {
#pragma unroll
    for (int q = 0; q < 4; q++) {
        int c = tid + q * 512;
        p[q] = *(const uint4*)(base + (size_t)(c >> 4) * HID + (c & 15) * 8);
    }
}

__device__ __forceinline__ void write_tile(const uint4 p[4], int tid, u16* s) {
#pragma unroll
    for (int q = 0; q < 4; q++) {
        int c = tid + q * 512;
        *(uint4*)(s + (c >> 4) * LDST + (c & 15) * 8) = p[q];
    }
}

__device__ __forceinline__ void stageFeat(const float* __restrict__ feat, int row0, int n, int tid, u16* sA) {
    int row = tid >> 2, coff = tid & 3;
    ushort4 o = make_ushort4(0, 0, 0, 0);
    if (row0 + row < n) {
        float4 v = *(const float4*)(feat + (size_t)(row0 + row) * IN_DIM + coff * 4);
        o = make_ushort4(f2b(v.x), f2b(v.y), f2b(v.z), f2b(v.w));
    }
    *(ushort4*)(sA + row * LDST + coff * 4) = o;
    *(ushort4*)(sA + row * LDST + 16 + coff * 4) = make_ushort4(0, 0, 0, 0);
}

__device__ __forceinline__ void stageW16(const u16* __restrict__ Wt, int tid, u16* sB) {
    if (tid < 256) {
        int row = tid >> 1, h8 = tid & 1;
        uint4 v = *(const uint4*)(Wt + row * IN_DIM + h8 * 8);
        *(uint4*)(sB + row * LDST + h8 * 8) = v;
        *(uint4*)(sB + row * LDST + 16 + h8 * 8) = make_uint4(0, 0, 0, 0);
    }
}

template <int KSTEPS>
__device__ __forceinline__ void mac(const u16* sA, const u16* sB, int wrow, int wcol,
                                    int ln15, int quad, f32x4 acc[2][4]) {
#pragma unroll
    for (int kk = 0; kk < KSTEPS; kk++) {
        short8 a[2], b[4];
#pragma unroll
        for (int mi = 0; mi < 2; mi++)
            a[mi] = *(const short8*)(sA + (wrow + mi * 16 + ln15) * LDST + kk * 32 + quad * 8);
#pragma unroll
        for (int ni = 0; ni < 4; ni++)
            b[ni] = *(const short8*)(sB + (wcol + ni * 16 + ln15) * LDST + kk * 32 + quad * 8);
#pragma unroll
        for (int mi = 0; mi < 2; mi++)
#pragma unroll
            for (int ni = 0; ni < 4; ni++)
                acc[mi][ni] = __builtin_amdgcn_mfma_f32_16x16x32_bf16(a[mi], b[ni], acc[mi][ni], 0, 0, 0);
    }
}

__device__ __forceinline__ void set_bias(f32x4 acc[2][4], const float* __restrict__ bias, int wcol, int ln15) {
#pragma unroll
    for (int ni = 0; ni < 4; ni++) {
        float bv = bias[wcol + ni * 16 + ln15];
#pragma unroll
        for (int mi = 0; mi < 2; mi++) acc[mi][ni] = (f32x4){bv, bv, bv, bv};
    }
}

__device__ __forceinline__ void acc_to_sA(const f32x4 acc[2][4], u16* sA, int wrow, int wcol,
                                          int ln15, int quad) {
#pragma unroll
    for (int mi = 0; mi < 2; mi++)
#pragma unroll
        for (int r = 0; r < 4; r++) {
            int row = wrow + mi * 16 + quad * 4 + r;
#pragma unroll
            for (int ni = 0; ni < 4; ni++)
                sA[row * LDST + wcol + ni * 16 + ln15] = f2b(fmaxf(acc[mi][ni][r], 0.f));
        }
}

// ---------------- fused init MLP (M=128) ----------------

__global__ __launch_bounds__(512, 4) void init_fused_k(const float* __restrict__ feat,
                                                       const u16* __restrict__ W0t, const u16* __restrict__ W1t,
                                                       const u16* __restrict__ W2t,
                                                       const float* __restrict__ b0, const float* __restrict__ b1,
                                                       const float* __restrict__ b2,
                                                       float* __restrict__ h, u16* __restrict__ hb,
                                                       float* __restrict__ gsum0, int n) {
    __shared__ u16 sA[128 * LDST];
    __shared__ u16 sB[128 * LDST];
    int tid = threadIdx.x;
    int lane = tid & 63, wave = tid >> 6;
    int ln15 = lane & 15, quad = lane >> 4;
    int wrow = (wave >> 1) * 32, wcol = (wave & 1) * 64;
    int row0 = blockIdx.x * 128;
    f32x4 acc[2][4];
    uint4 pB[4];

    stageFeat(feat, row0, n, tid, sA);
    stageW16(W0t, tid, sB);
    load_tile(W1t, tid, pB);
    set_bias(acc, b0, wcol, ln15);
    __syncthreads();
    mac<1>(sA, sB, wrow, wcol, ln15, quad, acc);
    __syncthreads();
    acc_to_sA(acc, sA, wrow, wcol, ln15, quad);
    write_tile(pB, tid, sB);
    load_tile(W2t, tid, pB);
    set_bias(acc, b1, wcol, ln15);
    __syncthreads();
    mac<4>(sA, sB, wrow, wcol, ln15, quad, acc);
    __syncthreads();
    acc_to_sA(acc, sA, wrow, wcol, ln15, quad);
    write_tile(pB, tid, sB);
    set_bias(acc, b2, wcol, ln15);
    __syncthreads();
    mac<4>(sA, sB, wrow, wcol, ln15, quad, acc);

    float csum[4] = {0.f, 0.f, 0.f, 0.f};
#pragma unroll
    for (int mi = 0; mi < 2; mi++)
#pragma unroll
        for (int r = 0; r < 4; r++) {
            int row = row0 + wrow + mi * 16 + quad * 4 + r;
            if (row < n) {
#pragma unroll
                for (int ni = 0; ni < 4; ni++) {
                    float v = acc[mi][ni][r];
                    int col = wcol + ni * 16 + ln15;
                    h[(size_t)row * HID + col] = v;
                    hb[(size_t)row * HID + col] = f2b(v);
                    csum[ni] += v;
                }
            }
        }
    __syncthreads();
    float* s_cs = (float*)sA;
    if (tid < HID) s_cs[tid] = 0.f;
    __syncthreads();
#pragma unroll
    for (int ni = 0; ni < 4; ni++) {
        float p = csum[ni];
        p += __shfl_xor(p, 16);
        p += __shfl_xor(p, 32);
        if (quad == 0) atomicAdd(&s_cs[wcol + ni * 16 + ln15], p);
    }
    __syncthreads();
    if (tid < HID) atomicAdd(&gsum0[tid], s_cs[tid]);
}

// ---------------- fused node update (M=128, register-prefetch pipeline) ----------------

template <bool FINAL>
__global__ __launch_bounds__(512, 4) void node_fused_k(const u16* __restrict__ msgb, const u16* __restrict__ hbin,
                                                       const u16* __restrict__ W0a, const u16* __restrict__ W0b,
                                                       const u16* __restrict__ W1t, const u16* __restrict__ W2t,
                                                       const float* __restrict__ grW,
                                                       const float* __restrict__ b1, const float* __restrict__ b2,
                                                       const int* __restrict__ deg,
                                                       float* __restrict__ h, u16* __restrict__ hb,
                                                       float* __restrict__ gsumOut, int n) {
    __shared__ u16 sA[128 * LDST];
    __shared__ u16 sB[128 * LDST];
    int tid = threadIdx.x;
    int lane = tid & 63, wave = tid >> 6;
    int ln15 = lane & 15, quad = lane >> 4;
    int wrow = (wave >> 1) * 32, wcol = (wave & 1) * 64;
    int row0 = blockIdx.x * 128;
    f32x4 acc[2][4];
    uint4 pA[4], pB[4];

    load_tile(msgb + (size_t)row0 * HID, tid, pA);
    load_tile(W0a, tid, pB);
    write_tile(pA, tid, sA);
    write_tile(pB, tid, sB);
    load_tile(hbin + (size_t)row0 * HID, tid, pA);
    load_tile(W0b, tid, pB);
    set_bias(acc, grW, wcol, ln15);
    __syncthreads();
    mac<4>(sA, sB, wrow, wcol, ln15, quad, acc);
    __syncthreads();
    write_tile(pA, tid, sA);
    write_tile(pB, tid, sB);
    load_tile(W1t, tid, pB);
    __syncthreads();
    mac<4>(sA, sB, wrow, wcol, ln15, quad, acc);
    __syncthreads();
    acc_to_sA(acc, sA, wrow, wcol, ln15, quad);
    write_tile(pB, tid, sB);
    load_tile(W2t, tid, pB);
    set_bias(acc, b1, wcol, ln15);
    __syncthreads();
    mac<4>(sA, sB, wrow, wcol, ln15, quad, acc);
    __syncthreads();
    acc_to_sA(acc, sA, wrow, wcol, ln15, quad);
    write_tile(pB, tid, sB);
    set_bias(acc, b2, wcol, ln15);
    __syncthreads();
    mac<4>(sA, sB, wrow, wcol, ln15, quad, acc);

    __syncthreads();
    float* s_rs = (float*)sA;
    float* s_cs = (float*)sA + 128;
    if (tid < 128) s_rs[tid] = 0.f;
    else if (tid < 256) s_cs[tid - 128] = 0.f;
    __syncthreads();
#pragma unroll
    for (int mi = 0; mi < 2; mi++)
#pragma unroll
        for (int r = 0; r < 4; r++) {
            float p = 0.f;
#pragma unroll
            for (int ni = 0; ni < 4; ni++) { float v = acc[mi][ni][r]; p += v * v; }
            p += __shfl_xor(p, 1); p += __shfl_xor(p, 2);
            p += __shfl_xor(p, 4); p += __shfl_xor(p, 8);
            if (ln15 == 0) atomicAdd(&s_rs[wrow + mi * 16 + quad * 4 + r], p);
        }
    __syncthreads();
    float csum[4] = {0.f, 0.f, 0.f, 0.f};
#pragma unroll
    for (int mi = 0; mi < 2; mi++)
#pragma unroll
        for (int r = 0; r < 4; r++) {
            int rl = wrow + mi * 16 + quad * 4 + r;
            int row = row0 + rl;
            if (row < n) {
                bool upd = deg[row] > 0;
                float inv = 1.f / (sqrtf(s_rs[rl]) + 1e-8f);
#pragma unroll
                for (int ni = 0; ni < 4; ni++) {
                    int col = wcol + ni * 16 + ln15;
                    if (FINAL) {
                        if (upd) h[(size_t)row * HID + col] = acc[mi][ni][r] * inv;
                    } else {
                        float v;
                        if (upd) {
                            v = acc[mi][ni][r] * inv;
                            hb[(size_t)row * HID + col] = f2b(v);
                        } else {
                            v = h[(size_t)row * HID + col];
                        }
                        csum[ni] += v;
                    }
                }
            }
        }
    if (!FINAL) {
#pragma unroll
        for (int ni = 0; ni < 4; ni++) {
            float p = csum[ni];
            p += __shfl_xor(p, 16);
            p += __shfl_xor(p, 32);
            if (quad == 0) atomicAdd(&s_cs[wcol + ni * 16 + ln15], p);
        }
        __syncthreads();
        if (tid < HID) atomicAdd(&gsumOut[tid], s_cs[tid]);
    }
}

// ---------------- launch ----------------

static inline char* align_up(char* p, size_t a) {
    return (char*)(((uintptr_t)p + a - 1) & ~(uintptr_t)(a - 1));
}

extern "C" void kernel_launch(void* const* d_in, const int* in_sizes, int n_in,
                              void* d_out, int out_size, void* d_ws, size_t ws_size,
                              hipStream_t stream) {
    const float* feat = (const float*)d_in[0];
    const int* src = (const int*)d_in[1];
    const int* dst = (const int*)d_in[2];
    const float* iW0 = (const float*)d_in[3];
    const float* ib0 = (const float*)d_in[4];
    const float* iW1 = (const float*)d_in[5];
    const float* ib1 = (const float*)d_in[6];
    const float* iW2 = (const float*)d_in[7];
    const float* ib2 = (const float*)d_in[8];
    const float* nW0 = (const float*)d_in[9];
    const float* nb0 = (const float*)d_in[10];
    const float* nW1 = (const float*)d_in[11];
    const float* nb1 = (const float*)d_in[12];
    const float* nW2 = (const float*)d_in[13];
    const float* nb2 = (const float*)d_in[14];

    int N = in_sizes[0] / IN_DIM;
    int E = in_sizes[1];
    int n_iter = in_sizes[10] / HID;
    int NB = (N + (1 << NBSH) - 1) >> NBSH;
    float* h = (float*)d_out;

    char* w = (char*)d_ws;
    size_t big2 = (size_t)(N + 128) * HID * sizeof(u16);
    u16* hb   = (u16*)w; w += big2;
    u16* msgb = (u16*)w; w += big2;
    float* gsums = (float*)w; w += (size_t)(n_iter + 1) * HID * sizeof(float);
    float* grW = (float*)w; w += 1024;
    u16* Wt = (u16*)w; w += (size_t)(2048 + 2 * 16384 + n_iter * 4 * 16384) * sizeof(u16);
    w = align_up(w, 16);
    int* deg = (int*)w; w += (size_t)N * 4;  w = align_up(w, 16);
    int* row_ptr = (int*)w; w += (size_t)(N + 1) * 4;  w = align_up(w, 16);
    int* bktcnt = (int*)w; w += (size_t)NB * 4;  w = align_up(w, 16);
    int* bktbase = (int*)w; w += (size_t)(NB + 1) * 4;  w = align_up(w, 64);
    int* bcnt = (int*)w; w += (size_t)NB * BPAD * 4;  w = align_up(w, 16);
    int* srcs = (int*)w; w += (size_t)E * 4;  w = align_up(w, 16);
    unsigned* ebuf = (unsigned*)w; w += (size_t)E * 4;
    (void)ws_size; (void)n_in; (void)out_size;

    const int OFF_IW0 = 0;
    const int OFF_IW1 = 2048;
    const int OFF_IW2 = 2048 + 16384;
    const int OFF_IT = 2048 + 2 * 16384;

    WJobs jobs;
    int nj = 0;
    jobs.src[nj] = iW0; jobs.dstoff[nj] = OFF_IW0; jobs.ks[nj] = 4; nj++;
    jobs.src[nj] = iW1; jobs.dstoff[nj] = OFF_IW1; jobs.ks[nj] = 7; nj++;
    jobs.src[nj] = iW2; jobs.dstoff[nj] = OFF_IW2; jobs.ks[nj] = 7; nj++;
    for (int i = 0; i < n_iter && nj + 4 <= 16; i++) {
        int base = OFF_IT + i * 4 * 16384;
        jobs.src[nj] = nW0 + (size_t)i * 3 * HID * HID;               jobs.dstoff[nj] = base;             jobs.ks[nj] = 7; nj++;
        jobs.src[nj] = nW0 + (size_t)i * 3 * HID * HID + HID * HID;   jobs.dstoff[nj] = base + 16384;     jobs.ks[nj] = 7; nj++;
        jobs.src[nj] = nW1 + (size_t)i * HID * HID;                   jobs.dstoff[nj] = base + 2 * 16384; jobs.ks[nj] = 7; nj++;
        jobs.src[nj] = nW2 + (size_t)i * HID * HID;                   jobs.dstoff[nj] = base + 3 * 16384; jobs.ks[nj] = 7; nj++;
    }

    hipMemsetAsync(bktcnt, 0, (size_t)NB * 4, stream);
    hipMemsetAsync(gsums, 0, (size_t)(n_iter + 1) * HID * sizeof(float), stream);

    wprep_k<<<nj, 256, 0, stream>>>(jobs, Wt);

    int cg = (E + CH - 1) / CH;
    hist_k<<<cg, 256, 0, stream>>>(dst, bktcnt, E, NB);
    bscan_k<<<1, 1024, 0, stream>>>(bktcnt, bktbase, bcnt, row_ptr, NB, N, E);
    bin_k<<<cg, 256, 0, stream>>>(src, dst, bcnt, ebuf, E, NB);
    fill2_k<<<NB, 256, 0, stream>>>(ebuf, bktbase, row_ptr, deg, srcs, N);

    int gb = (N + 127) / 128;
    int rb = (N + 3) / 4;
    init_fused_k<<<gb, 512, 0, stream>>>(feat, Wt + OFF_IW0, Wt + OFF_IW1, Wt + OFF_IW2,
                                         ib0, ib1, ib2, h, hb, gsums, N);

    for (int i = 0; i < n_iter; i++) {
        const u16* Wit = Wt + OFF_IT + (size_t)i * 4 * 16384;
        const float* Wg = nW0 + (size_t)i * 3 * HID * HID + 2 * HID * HID;
        msg_k<<<rb + 1, 256, 0, stream>>>(hb, row_ptr, srcs, msgb, N,
                                          gsums + (size_t)i * HID, Wg, nb0 + (size_t)i * HID, grW);
        if (i + 1 < n_iter) {
            node_fused_k<false><<<gb, 512, 0, stream>>>(msgb, hb, Wit, Wit + 16384, Wit + 2 * 16384,
                                                        Wit + 3 * 16384, grW, nb1 + (size_t)i * HID,
                                                        nb2 + (size_t)i * HID, deg, h, hb,
                                                        gsums + (size_t)(i + 1) * HID, N);
        } else {
            node_fused_k<true><<<gb, 512, 0, stream>>>(msgb, hb, Wit, Wit + 16384, Wit + 2 * 16384,
                                                       Wit + 3 * 16384, grW, nb1 + (size_t)i * HID,
                                                       nb2 + (size_t)i * HID, deg, h, hb,
                                                       nullptr, N);
        }
    }
}